// Round 1
// baseline (900.194 us; speedup 1.0000x reference)
//
#include <hip/hip_runtime.h>
#include <math.h>

#define NNODES 50000

// ---------------- CSR build ----------------
__global__ __launch_bounds__(256) void deg_init_kernel(int* __restrict__ deg, int N) {
    int i = blockIdx.x * 256 + threadIdx.x;
    if (i < N) deg[i] = 1;  // self-loop
}

__global__ __launch_bounds__(256) void deg_count_kernel(const int* __restrict__ ei,
                                                        int* __restrict__ deg, int E) {
    int i = blockIdx.x * 256 + threadIdx.x;
    if (i < E) atomicAdd(&deg[ei[E + i]], 1);
}

__global__ __launch_bounds__(1024) void scan_kernel(const int* __restrict__ deg,
                                                    int* __restrict__ rowptr,
                                                    int* __restrict__ fill, int N) {
    __shared__ int sums[1024];
    int t = threadIdx.x;
    int chunk = (N + 1023) / 1024;
    int lo = t * chunk;
    int hi = lo + chunk; if (hi > N) hi = N;
    int s = 0;
    for (int i = lo; i < hi; ++i) s += deg[i];
    sums[t] = s;
    __syncthreads();
    for (int off = 1; off < 1024; off <<= 1) {
        int v = (t >= off) ? sums[t - off] : 0;
        __syncthreads();
        sums[t] += v;
        __syncthreads();
    }
    int run = (t == 0) ? 0 : sums[t - 1];
    for (int i = lo; i < hi; ++i) {
        rowptr[i] = run;
        fill[i] = run;
        run += deg[i];
    }
    if (t == 1023) rowptr[N] = sums[1023];
}

__global__ __launch_bounds__(256) void scatter_kernel(const int* __restrict__ ei,
                                                      int* __restrict__ fill,
                                                      int* __restrict__ col, int E, int N) {
    int i = blockIdx.x * 256 + threadIdx.x;
    int total = E + N;
    if (i >= total) return;
    int s, d;
    if (i < E) { s = ei[i]; d = ei[E + i]; }
    else       { s = i - E; d = s; }
    int pos = atomicAdd(&fill[d], 1);
    col[pos] = s;
}

// ---------------- fp32 tiled GEMM: C[M,Ncol] = A[M,K] @ B[K,Ncol] ----------------
// 64x64 tile per 256-thread block, 4x4 micro-tile, K-step 16. K, Ncol multiples of 16/64.
__global__ __launch_bounds__(256) void gemm_kernel(const float* __restrict__ A,
                                                   const float* __restrict__ B,
                                                   float* __restrict__ C,
                                                   int M, int K, int Ncol) {
    __shared__ __align__(16) float As[16][64];  // [k][m]
    __shared__ __align__(16) float Bs[16][64];  // [k][n]
    int tid = threadIdx.x;
    int bm = blockIdx.x * 64;
    int bn = blockIdx.y * 64;
    int tm = (tid >> 4) * 4;
    int tn = (tid & 15) * 4;
    float acc[4][4] = {};
    int ar  = tid >> 2;        // 0..63 row of A tile
    int akk = (tid & 3) * 4;   // 0,4,8,12
    int brr = tid >> 4;        // 0..15 row of B tile
    int bcc = (tid & 15) * 4;
    for (int k0 = 0; k0 < K; k0 += 16) {
        int grow = bm + ar;
        float4 av;
        if (grow < M) av = *reinterpret_cast<const float4*>(A + (size_t)grow * K + k0 + akk);
        else          av = make_float4(0.f, 0.f, 0.f, 0.f);
        As[akk + 0][ar] = av.x;
        As[akk + 1][ar] = av.y;
        As[akk + 2][ar] = av.z;
        As[akk + 3][ar] = av.w;
        float4 bv = *reinterpret_cast<const float4*>(B + (size_t)(k0 + brr) * Ncol + bn + bcc);
        *reinterpret_cast<float4*>(&Bs[brr][bcc]) = bv;
        __syncthreads();
        #pragma unroll
        for (int kk = 0; kk < 16; ++kk) {
            float4 a4 = *reinterpret_cast<const float4*>(&As[kk][tm]);
            float4 b4 = *reinterpret_cast<const float4*>(&Bs[kk][tn]);
            float a[4] = {a4.x, a4.y, a4.z, a4.w};
            float b[4] = {b4.x, b4.y, b4.z, b4.w};
            #pragma unroll
            for (int i = 0; i < 4; ++i)
                #pragma unroll
                for (int j = 0; j < 4; ++j) acc[i][j] += a[i] * b[j];
        }
        __syncthreads();
    }
    #pragma unroll
    for (int i = 0; i < 4; ++i) {
        int gr = bm + tm + i;
        if (gr < M) {
            float4 r = make_float4(acc[i][0], acc[i][1], acc[i][2], acc[i][3]);
            *reinterpret_cast<float4*>(C + (size_t)gr * Ncol + bn + tn) = r;
        }
    }
}

// ---------------- attention coefficients: es/ed per (node, head) ----------------
template <int H>
__global__ __launch_bounds__(256) void attn_kernel(const float* __restrict__ h,
                                                   const float* __restrict__ as_,
                                                   const float* __restrict__ ad_,
                                                   float* __restrict__ es,
                                                   float* __restrict__ ed, int N) {
    int node = blockIdx.x * 4 + (threadIdx.x >> 6);
    if (node >= N) return;
    int lane = threadIdx.x & 63;
    const float* hp = h + (size_t)node * (H * 64);
    float sv[H], dv[H];
    #pragma unroll
    for (int hh = 0; hh < H; ++hh) {
        float v = hp[hh * 64 + lane];
        sv[hh] = v * as_[hh * 64 + lane];
        dv[hh] = v * ad_[hh * 64 + lane];
    }
    #pragma unroll
    for (int off = 32; off; off >>= 1) {
        #pragma unroll
        for (int hh = 0; hh < H; ++hh) {
            sv[hh] += __shfl_xor(sv[hh], off, 64);
            dv[hh] += __shfl_xor(dv[hh], off, 64);
        }
    }
    if (lane == 0) {
        #pragma unroll
        for (int hh = 0; hh < H; ++hh) {
            es[node * H + hh] = sv[hh];
            ed[node * H + hh] = dv[hh];
        }
    }
}

__device__ __forceinline__ float lrelu02(float x) { return x > 0.f ? x : 0.2f * x; }
__device__ __forceinline__ float eluf(float x)    { return x > 0.f ? x : expm1f(x); }

// ---------------- per-dst aggregation: softmax over incoming edges + weighted sum ----------------
// One 64-lane wave per destination node. 3 register passes over the node's CSR edge list.
template <int H, int ACT>
__global__ __launch_bounds__(256) void agg_kernel(const float* __restrict__ hbuf,
                                                  const float* __restrict__ es,
                                                  const float* __restrict__ ed,
                                                  const int* __restrict__ rowptr,
                                                  const int* __restrict__ col,
                                                  const float* __restrict__ bias,
                                                  float* __restrict__ out, int N) {
    int node = blockIdx.x * 4 + (threadIdx.x >> 6);
    if (node >= N) return;
    int lane = threadIdx.x & 63;
    int s = rowptr[node], t = rowptr[node + 1];

    float edv[H], mx[H], den[H];
    #pragma unroll
    for (int h = 0; h < H; ++h) { edv[h] = ed[node * H + h]; mx[h] = -INFINITY; den[h] = 0.f; }

    // pass 1: segment max (edges strided over lanes)
    for (int j = s + lane; j < t; j += 64) {
        int sc = col[j];
        #pragma unroll
        for (int h = 0; h < H; ++h) {
            float e = lrelu02(es[sc * H + h] + edv[h]);
            mx[h] = fmaxf(mx[h], e);
        }
    }
    #pragma unroll
    for (int off = 32; off; off >>= 1)
        #pragma unroll
        for (int h = 0; h < H; ++h) mx[h] = fmaxf(mx[h], __shfl_xor(mx[h], off, 64));

    // pass 2: denominator
    for (int j = s + lane; j < t; j += 64) {
        int sc = col[j];
        #pragma unroll
        for (int h = 0; h < H; ++h) {
            float e = lrelu02(es[sc * H + h] + edv[h]);
            den[h] += __expf(e - mx[h]);
        }
    }
    #pragma unroll
    for (int off = 32; off; off >>= 1)
        #pragma unroll
        for (int h = 0; h < H; ++h) den[h] += __shfl_xor(den[h], off, 64);
    float inv[H];
    #pragma unroll
    for (int h = 0; h < H; ++h) inv[h] = 1.f / den[h];

    // pass 3: weighted aggregation (all lanes walk edges together)
    if constexpr (H == 4) {
        int hh = lane >> 4;          // lane's head (4 consecutive dims per lane)
        int base = lane * 4;
        float edh = edv[hh], mxh = mx[hh], invh = inv[hh];
        float4 acc = make_float4(0.f, 0.f, 0.f, 0.f);
        for (int j = s; j < t; ++j) {
            int sc = col[j];
            float e = lrelu02(es[sc * 4 + hh] + edh);
            float alpha = __expf(e - mxh) * invh;
            float4 hv = *reinterpret_cast<const float4*>(hbuf + (size_t)sc * 256 + base);
            acc.x += hv.x * alpha;
            acc.y += hv.y * alpha;
            acc.z += hv.z * alpha;
            acc.w += hv.w * alpha;
        }
        float4 bv = *reinterpret_cast<const float4*>(bias + base);
        float4 r;
        r.x = acc.x + bv.x; r.y = acc.y + bv.y; r.z = acc.z + bv.z; r.w = acc.w + bv.w;
        if (ACT) { r.x = eluf(r.x); r.y = eluf(r.y); r.z = eluf(r.z); r.w = eluf(r.w); }
        *reinterpret_cast<float4*>(out + (size_t)node * 256 + base) = r;
    } else {  // H == 1, D = 64
        float acc = 0.f;
        float edh = edv[0], mxh = mx[0], invh = inv[0];
        for (int j = s; j < t; ++j) {
            int sc = col[j];
            float e = lrelu02(es[sc] + edh);
            float alpha = __expf(e - mxh) * invh;
            acc += hbuf[(size_t)sc * 64 + lane] * alpha;
        }
        float r = acc + bias[lane];
        if (ACT) r = eluf(r);
        out[(size_t)node * 64 + lane] = r;
    }
}

// ---------------- graph mean ----------------
__global__ __launch_bounds__(256) void gmean_partial(const float* __restrict__ ne,
                                                     float* __restrict__ part, int N) {
    int d = threadIdx.x & 63, sub = threadIdx.x >> 6;
    int start = blockIdx.x * 4 + sub;
    float s = 0.f;
    for (int n = start; n < N; n += gridDim.x * 4) s += ne[(size_t)n * 64 + d];
    __shared__ float ls[256];
    ls[threadIdx.x] = s;
    __syncthreads();
    if (threadIdx.x < 64) {
        float v = ls[threadIdx.x] + ls[threadIdx.x + 64] + ls[threadIdx.x + 128] + ls[threadIdx.x + 192];
        part[blockIdx.x * 64 + d] = v;
    }
}

__global__ __launch_bounds__(64) void gmean_final(const float* __restrict__ part,
                                                  float* __restrict__ gout, int nblk, float invN) {
    int d = threadIdx.x;
    float s = 0.f;
    for (int b = 0; b < nblk; ++b) s += part[b * 64 + d];
    gout[d] = s * invN;
}

extern "C" void kernel_launch(void* const* d_in, const int* in_sizes, int n_in,
                              void* d_out, int out_size, void* d_ws, size_t ws_size,
                              hipStream_t stream) {
    const float* x   = (const float*)d_in[0];
    const int*   ei  = (const int*)d_in[1];
    const float* W1  = (const float*)d_in[2];
    const float* a1s = (const float*)d_in[3];
    const float* a1d = (const float*)d_in[4];
    const float* b1  = (const float*)d_in[5];
    const float* W2  = (const float*)d_in[6];
    const float* a2s = (const float*)d_in[7];
    const float* a2d = (const float*)d_in[8];
    const float* b2  = (const float*)d_in[9];
    const float* W3  = (const float*)d_in[10];
    const float* a3s = (const float*)d_in[11];
    const float* a3d = (const float*)d_in[12];
    const float* b3  = (const float*)d_in[13];
    float* out = (float*)d_out;

    const int N = NNODES;
    const int E = in_sizes[1] / 2;  // 800000

    // workspace carve (all offsets keep 16B alignment for the big float buffers)
    char* w = (char*)d_ws;
    float* B0 = (float*)w; w += (size_t)N * 256 * 4;   // h buffer
    float* B1 = (float*)w; w += (size_t)N * 256 * 4;   // layer output ping-pong
    float* es = (float*)w; w += (size_t)N * 4 * 4;
    float* ed = (float*)w; w += (size_t)N * 4 * 4;
    int* deg    = (int*)w; w += (size_t)N * 4;
    int* rowptr = (int*)w; w += (size_t)(N + 2) * 4;
    int* fill   = (int*)w; w += (size_t)N * 4;
    int* col    = (int*)w; w += (size_t)(E + N) * 4;
    float* part = (float*)w; w += 128 * 64 * 4;
    (void)ws_size; (void)n_in; (void)out_size;

    // ---- CSR build (dst-sorted adjacency incl. self-loops) ----
    deg_init_kernel<<<(N + 255) / 256, 256, 0, stream>>>(deg, N);
    deg_count_kernel<<<(E + 255) / 256, 256, 0, stream>>>(ei, deg, E);
    scan_kernel<<<1, 1024, 0, stream>>>(deg, rowptr, fill, N);
    scatter_kernel<<<(E + N + 255) / 256, 256, 0, stream>>>(ei, fill, col, E, N);

    // ---- Layer 1: x[N,16] @ W1[16,256] ----
    gemm_kernel<<<dim3((N + 63) / 64, 4), 256, 0, stream>>>(x, W1, B0, N, 16, 256);
    attn_kernel<4><<<(N + 3) / 4, 256, 0, stream>>>(B0, a1s, a1d, es, ed, N);
    agg_kernel<4, 1><<<(N + 3) / 4, 256, 0, stream>>>(B0, es, ed, rowptr, col, b1, B1, N);

    // ---- Layer 2: B1[N,256] @ W2[256,256] ----
    gemm_kernel<<<dim3((N + 63) / 64, 4), 256, 0, stream>>>(B1, W2, B0, N, 256, 256);
    attn_kernel<4><<<(N + 3) / 4, 256, 0, stream>>>(B0, a2s, a2d, es, ed, N);
    agg_kernel<4, 1><<<(N + 3) / 4, 256, 0, stream>>>(B0, es, ed, rowptr, col, b2, B1, N);

    // ---- Layer 3: B1[N,256] @ W3[256,64], H=1, no activation ----
    gemm_kernel<<<dim3((N + 63) / 64, 1), 256, 0, stream>>>(B1, W3, B0, N, 256, 64);
    attn_kernel<1><<<(N + 3) / 4, 256, 0, stream>>>(B0, a3s, a3d, es, ed, N);
    agg_kernel<1, 0><<<(N + 3) / 4, 256, 0, stream>>>(B0, es, ed, rowptr, col, b3, out, N);

    // ---- graph mean over nodes ----
    gmean_partial<<<128, 256, 0, stream>>>(out, part, N);
    gmean_final<<<1, 64, 0, stream>>>(part, out + (size_t)N * 64, 128, 1.0f / N);
}

// Round 2
// 782.276 us; speedup vs baseline: 1.1507x; 1.1507x over previous
//
#include <hip/hip_runtime.h>
#include <math.h>

#define NNODES 50000

// ---------------- CSR build ----------------
__global__ __launch_bounds__(256) void deg_init_kernel(int* __restrict__ deg, int N) {
    int i = blockIdx.x * 256 + threadIdx.x;
    if (i < N) deg[i] = 1;  // self-loop
}

__global__ __launch_bounds__(256) void deg_count_kernel(const int* __restrict__ ei,
                                                        int* __restrict__ deg, int E) {
    int i = blockIdx.x * 256 + threadIdx.x;
    if (i < E) atomicAdd(&deg[ei[E + i]], 1);
}

__global__ __launch_bounds__(1024) void scan_kernel(const int* __restrict__ deg,
                                                    int* __restrict__ rowptr,
                                                    int* __restrict__ fill, int N) {
    __shared__ int sums[1024];
    int t = threadIdx.x;
    int chunk = (N + 1023) / 1024;
    int lo = t * chunk;
    int hi = lo + chunk; if (hi > N) hi = N;
    int s = 0;
    for (int i = lo; i < hi; ++i) s += deg[i];
    sums[t] = s;
    __syncthreads();
    for (int off = 1; off < 1024; off <<= 1) {
        int v = (t >= off) ? sums[t - off] : 0;
        __syncthreads();
        sums[t] += v;
        __syncthreads();
    }
    int run = (t == 0) ? 0 : sums[t - 1];
    for (int i = lo; i < hi; ++i) {
        rowptr[i] = run;
        fill[i] = run;
        run += deg[i];
    }
    if (t == 1023) rowptr[N] = sums[1023];
}

__global__ __launch_bounds__(256) void scatter_kernel(const int* __restrict__ ei,
                                                      int* __restrict__ fill,
                                                      int* __restrict__ col, int E, int N) {
    int i = blockIdx.x * 256 + threadIdx.x;
    int total = E + N;
    if (i >= total) return;
    int s, d;
    if (i < E) { s = ei[i]; d = ei[E + i]; }
    else       { s = i - E; d = s; }
    int pos = atomicAdd(&fill[d], 1);
    col[pos] = s;
}

// ---------------- fp32 tiled GEMM with fused attention-coefficient epilogue ----------------
// C[M,Ncol] = A[M,K] @ B[K,Ncol]; 64x64 tile per 256-thread block, 4x4 micro-tile.
// Each blockIdx.y tile spans exactly one head (64 cols), so the epilogue computes
// es/ed = <h_row, a_s/a_d> for that head via in-register dot + 16-lane shuffle reduce.
template <int H>
__global__ __launch_bounds__(256) void gemm_attn_kernel(const float* __restrict__ A,
                                                        const float* __restrict__ B,
                                                        float* __restrict__ C,
                                                        const float* __restrict__ as_,
                                                        const float* __restrict__ ad_,
                                                        float* __restrict__ es,
                                                        float* __restrict__ ed,
                                                        int M, int K, int Ncol) {
    __shared__ __align__(16) float As[16][64];  // [k][m]
    __shared__ __align__(16) float Bs[16][64];  // [k][n]
    int tid = threadIdx.x;
    int bm = blockIdx.x * 64;
    int bn = blockIdx.y * 64;
    int tm = (tid >> 4) * 4;
    int tn = (tid & 15) * 4;
    float acc[4][4] = {};
    int ar  = tid >> 2;        // 0..63 row of A tile
    int akk = (tid & 3) * 4;   // 0,4,8,12
    int brr = tid >> 4;        // 0..15 row of B tile
    int bcc = (tid & 15) * 4;
    for (int k0 = 0; k0 < K; k0 += 16) {
        int grow = bm + ar;
        float4 av;
        if (grow < M) av = *reinterpret_cast<const float4*>(A + (size_t)grow * K + k0 + akk);
        else          av = make_float4(0.f, 0.f, 0.f, 0.f);
        As[akk + 0][ar] = av.x;
        As[akk + 1][ar] = av.y;
        As[akk + 2][ar] = av.z;
        As[akk + 3][ar] = av.w;
        float4 bv = *reinterpret_cast<const float4*>(B + (size_t)(k0 + brr) * Ncol + bn + bcc);
        *reinterpret_cast<float4*>(&Bs[brr][bcc]) = bv;
        __syncthreads();
        #pragma unroll
        for (int kk = 0; kk < 16; ++kk) {
            float4 a4 = *reinterpret_cast<const float4*>(&As[kk][tm]);
            float4 b4 = *reinterpret_cast<const float4*>(&Bs[kk][tn]);
            float a[4] = {a4.x, a4.y, a4.z, a4.w};
            float b[4] = {b4.x, b4.y, b4.z, b4.w};
            #pragma unroll
            for (int i = 0; i < 4; ++i)
                #pragma unroll
                for (int j = 0; j < 4; ++j) acc[i][j] += a[i] * b[j];
        }
        __syncthreads();
    }
    #pragma unroll
    for (int i = 0; i < 4; ++i) {
        int gr = bm + tm + i;
        if (gr < M) {
            float4 r = make_float4(acc[i][0], acc[i][1], acc[i][2], acc[i][3]);
            *reinterpret_cast<float4*>(C + (size_t)gr * Ncol + bn + tn) = r;
        }
    }
    // ---- fused es/ed epilogue ----
    int hy = blockIdx.y;  // head index (Ncol == H*64)
    float4 asv = *reinterpret_cast<const float4*>(as_ + (size_t)hy * 64 + tn);
    float4 adv = *reinterpret_cast<const float4*>(ad_ + (size_t)hy * 64 + tn);
    float sv[4], dv[4];
    #pragma unroll
    for (int i = 0; i < 4; ++i) {
        sv[i] = acc[i][0] * asv.x + acc[i][1] * asv.y + acc[i][2] * asv.z + acc[i][3] * asv.w;
        dv[i] = acc[i][0] * adv.x + acc[i][1] * adv.y + acc[i][2] * adv.z + acc[i][3] * adv.w;
    }
    #pragma unroll
    for (int off = 1; off < 16; off <<= 1) {
        #pragma unroll
        for (int i = 0; i < 4; ++i) {
            sv[i] += __shfl_xor(sv[i], off, 64);
            dv[i] += __shfl_xor(dv[i], off, 64);
        }
    }
    if ((tid & 15) == 0) {
        #pragma unroll
        for (int i = 0; i < 4; ++i) {
            int gr = bm + tm + i;
            if (gr < M) {
                es[(size_t)gr * H + hy] = sv[i];
                ed[(size_t)gr * H + hy] = dv[i];
            }
        }
    }
}

__device__ __forceinline__ float lrelu02(float x) { return x > 0.f ? x : 0.2f * x; }
__device__ __forceinline__ float eluf(float x)    { return x > 0.f ? x : expm1f(x); }

// ---------------- fused per-dst aggregation ----------------
// One 64-lane wave per destination node, 4 nodes per block. Per 64-edge chunk:
// coalesced col/es loads -> softmax weights p in LDS -> gather loop with all
// addresses known up front (unrolled, many outstanding loads). Accumulates
// unnormalized sum + denominator; divides once at the end.
template <int H, int ACT>
__global__ __launch_bounds__(256) void agg_fused_kernel(const float* __restrict__ hbuf,
                                                        const float* __restrict__ es,
                                                        const float* __restrict__ ed,
                                                        const int* __restrict__ rowptr,
                                                        const int* __restrict__ col,
                                                        const float* __restrict__ bias,
                                                        float* __restrict__ out, int N) {
    __shared__ int   slds[4][64];
    __shared__ float plds[4][H][64];
    int sub  = threadIdx.x >> 6;
    int lane = threadIdx.x & 63;
    int node = blockIdx.x * 4 + sub;
    if (node >= N) return;
    int s = rowptr[node], t = rowptr[node + 1];

    float edv[H];
    #pragma unroll
    for (int h = 0; h < H; ++h) edv[h] = ed[(size_t)node * H + h];

    // phase A: global max per head (coalesced, one iteration for deg <= 64)
    float mx[H];
    #pragma unroll
    for (int h = 0; h < H; ++h) mx[h] = -3.0e38f;
    for (int base = s; base < t; base += 64) {
        int j = base + lane;
        if (j < t) {
            int sc = col[j];
            if constexpr (H == 4) {
                float4 e4 = *reinterpret_cast<const float4*>(es + (size_t)sc * 4);
                mx[0] = fmaxf(mx[0], lrelu02(e4.x + edv[0]));
                mx[1] = fmaxf(mx[1], lrelu02(e4.y + edv[1]));
                mx[2] = fmaxf(mx[2], lrelu02(e4.z + edv[2]));
                mx[3] = fmaxf(mx[3], lrelu02(e4.w + edv[3]));
            } else {
                mx[0] = fmaxf(mx[0], lrelu02(es[sc] + edv[0]));
            }
        }
    }
    #pragma unroll
    for (int off = 32; off; off >>= 1)
        #pragma unroll
        for (int h = 0; h < H; ++h) mx[h] = fmaxf(mx[h], __shfl_xor(mx[h], off, 64));

    // phase B: weights -> LDS, unnormalized gather-accumulate
    float den[H];
    #pragma unroll
    for (int h = 0; h < H; ++h) den[h] = 0.f;

    if constexpr (H == 4) {
        int hh = lane >> 4;  // this lane's head (4 dims per lane)
        float4 acc = make_float4(0.f, 0.f, 0.f, 0.f);
        for (int base = s; base < t; base += 64) {
            int j = base + lane;
            int m = t - base; if (m > 64) m = 64;
            int sc = 0;
            float p[4] = {0.f, 0.f, 0.f, 0.f};
            if (j < t) {
                sc = col[j];
                float4 e4 = *reinterpret_cast<const float4*>(es + (size_t)sc * 4);
                p[0] = __expf(lrelu02(e4.x + edv[0]) - mx[0]);
                p[1] = __expf(lrelu02(e4.y + edv[1]) - mx[1]);
                p[2] = __expf(lrelu02(e4.z + edv[2]) - mx[2]);
                p[3] = __expf(lrelu02(e4.w + edv[3]) - mx[3]);
            }
            slds[sub][lane] = sc;
            #pragma unroll
            for (int h = 0; h < 4; ++h) {
                den[h] += p[h];
                plds[sub][h][lane] = p[h];
            }
            #pragma unroll 4
            for (int jj = 0; jj < m; ++jj) {
                int scj = slds[sub][jj];
                float a = plds[sub][hh][jj];
                float4 hv = *reinterpret_cast<const float4*>(hbuf + (size_t)scj * 256 + lane * 4);
                acc.x += hv.x * a;
                acc.y += hv.y * a;
                acc.z += hv.z * a;
                acc.w += hv.w * a;
            }
        }
        #pragma unroll
        for (int off = 32; off; off >>= 1)
            #pragma unroll
            for (int h = 0; h < 4; ++h) den[h] += __shfl_xor(den[h], off, 64);
        float inv = 1.f / den[hh];
        float4 bv = *reinterpret_cast<const float4*>(bias + lane * 4);
        float4 r;
        r.x = acc.x * inv + bv.x;
        r.y = acc.y * inv + bv.y;
        r.z = acc.z * inv + bv.z;
        r.w = acc.w * inv + bv.w;
        if (ACT) { r.x = eluf(r.x); r.y = eluf(r.y); r.z = eluf(r.z); r.w = eluf(r.w); }
        *reinterpret_cast<float4*>(out + (size_t)node * 256 + lane * 4) = r;
    } else {  // H == 1, D = 64
        float acc = 0.f;
        for (int base = s; base < t; base += 64) {
            int j = base + lane;
            int m = t - base; if (m > 64) m = 64;
            int sc = 0;
            float p0 = 0.f;
            if (j < t) {
                sc = col[j];
                p0 = __expf(lrelu02(es[sc] + edv[0]) - mx[0]);
            }
            slds[sub][lane] = sc;
            plds[sub][0][lane] = p0;
            den[0] += p0;
            #pragma unroll 4
            for (int jj = 0; jj < m; ++jj) {
                int scj = slds[sub][jj];
                float a = plds[sub][0][jj];
                acc += hbuf[(size_t)scj * 64 + lane] * a;
            }
        }
        #pragma unroll
        for (int off = 32; off; off >>= 1) den[0] += __shfl_xor(den[0], off, 64);
        float r = acc * (1.f / den[0]) + bias[lane];
        if (ACT) r = eluf(r);
        out[(size_t)node * 64 + lane] = r;
    }
}

// ---------------- graph mean ----------------
__global__ __launch_bounds__(256) void gmean_partial(const float* __restrict__ ne,
                                                     float* __restrict__ part, int N) {
    int d = threadIdx.x & 63, sub = threadIdx.x >> 6;
    int start = blockIdx.x * 4 + sub;
    float s = 0.f;
    for (int n = start; n < N; n += gridDim.x * 4) s += ne[(size_t)n * 64 + d];
    __shared__ float ls[256];
    ls[threadIdx.x] = s;
    __syncthreads();
    if (threadIdx.x < 64) {
        float v = ls[threadIdx.x] + ls[threadIdx.x + 64] + ls[threadIdx.x + 128] + ls[threadIdx.x + 192];
        part[blockIdx.x * 64 + d] = v;
    }
}

__global__ __launch_bounds__(64) void gmean_final(const float* __restrict__ part,
                                                  float* __restrict__ gout, int nblk, float invN) {
    int d = threadIdx.x;
    float s = 0.f;
    for (int b = 0; b < nblk; ++b) s += part[b * 64 + d];
    gout[d] = s * invN;
}

extern "C" void kernel_launch(void* const* d_in, const int* in_sizes, int n_in,
                              void* d_out, int out_size, void* d_ws, size_t ws_size,
                              hipStream_t stream) {
    const float* x   = (const float*)d_in[0];
    const int*   ei  = (const int*)d_in[1];
    const float* W1  = (const float*)d_in[2];
    const float* a1s = (const float*)d_in[3];
    const float* a1d = (const float*)d_in[4];
    const float* b1  = (const float*)d_in[5];
    const float* W2  = (const float*)d_in[6];
    const float* a2s = (const float*)d_in[7];
    const float* a2d = (const float*)d_in[8];
    const float* b2  = (const float*)d_in[9];
    const float* W3  = (const float*)d_in[10];
    const float* a3s = (const float*)d_in[11];
    const float* a3d = (const float*)d_in[12];
    const float* b3  = (const float*)d_in[13];
    float* out = (float*)d_out;

    const int N = NNODES;
    const int E = in_sizes[1] / 2;  // 800000

    // workspace carve
    char* w = (char*)d_ws;
    float* B0 = (float*)w; w += (size_t)N * 256 * 4;   // h buffer
    float* B1 = (float*)w; w += (size_t)N * 256 * 4;   // layer output ping-pong
    float* es = (float*)w; w += (size_t)N * 4 * 4;
    float* ed = (float*)w; w += (size_t)N * 4 * 4;
    int* deg    = (int*)w; w += (size_t)N * 4;
    int* rowptr = (int*)w; w += (size_t)(N + 2) * 4;
    int* fill   = (int*)w; w += (size_t)N * 4;
    int* col    = (int*)w; w += (size_t)(E + N) * 4;
    float* part = (float*)w; w += 128 * 64 * 4;
    (void)ws_size; (void)n_in; (void)out_size;

    // ---- CSR build (dst-sorted adjacency incl. self-loops) ----
    deg_init_kernel<<<(N + 255) / 256, 256, 0, stream>>>(deg, N);
    deg_count_kernel<<<(E + 255) / 256, 256, 0, stream>>>(ei, deg, E);
    scan_kernel<<<1, 1024, 0, stream>>>(deg, rowptr, fill, N);
    scatter_kernel<<<(E + N + 255) / 256, 256, 0, stream>>>(ei, fill, col, E, N);

    // ---- Layer 1: x[N,16] @ W1[16,256], H=4 ----
    gemm_attn_kernel<4><<<dim3((N + 63) / 64, 4), 256, 0, stream>>>(x, W1, B0, a1s, a1d, es, ed, N, 16, 256);
    agg_fused_kernel<4, 1><<<(N + 3) / 4, 256, 0, stream>>>(B0, es, ed, rowptr, col, b1, B1, N);

    // ---- Layer 2: B1[N,256] @ W2[256,256], H=4 ----
    gemm_attn_kernel<4><<<dim3((N + 63) / 64, 4), 256, 0, stream>>>(B1, W2, B0, a2s, a2d, es, ed, N, 256, 256);
    agg_fused_kernel<4, 1><<<(N + 3) / 4, 256, 0, stream>>>(B0, es, ed, rowptr, col, b2, B1, N);

    // ---- Layer 3: B1[N,256] @ W3[256,64], H=1, no activation ----
    gemm_attn_kernel<1><<<dim3((N + 63) / 64, 1), 256, 0, stream>>>(B1, W3, B0, a3s, a3d, es, ed, N, 256, 64);
    agg_fused_kernel<1, 0><<<(N + 3) / 4, 256, 0, stream>>>(B0, es, ed, rowptr, col, b3, out, N);

    // ---- graph mean over nodes ----
    gmean_partial<<<128, 256, 0, stream>>>(out, part, N);
    gmean_final<<<1, 64, 0, stream>>>(part, out + (size_t)N * 64, 128, 1.0f / N);
}

// Round 3
// 664.947 us; speedup vs baseline: 1.3538x; 1.1764x over previous
//
#include <hip/hip_runtime.h>
#include <math.h>

#define NNODES 50000

__device__ __forceinline__ unsigned short f2bf(float f) {
    unsigned u = __float_as_uint(f);
    u += 0x7fffu + ((u >> 16) & 1);   // RTN-even
    return (unsigned short)(u >> 16);
}

// ---------------- CSR build ----------------
__global__ __launch_bounds__(256) void deg_init_kernel(int* __restrict__ deg, int N) {
    int i = blockIdx.x * 256 + threadIdx.x;
    if (i < N) deg[i] = 1;  // self-loop
}

__global__ __launch_bounds__(256) void deg_count_kernel(const int* __restrict__ ei,
                                                        int* __restrict__ deg, int E) {
    int i = blockIdx.x * 256 + threadIdx.x;
    if (i < E) atomicAdd(&deg[ei[E + i]], 1);
}

__global__ __launch_bounds__(1024) void scan_kernel(const int* __restrict__ deg,
                                                    int* __restrict__ rowptr,
                                                    int* __restrict__ fill, int N) {
    __shared__ int sums[1024];
    int t = threadIdx.x;
    int chunk = (N + 1023) / 1024;
    int lo = t * chunk;
    int hi = lo + chunk; if (hi > N) hi = N;
    int s = 0;
    for (int i = lo; i < hi; ++i) s += deg[i];
    sums[t] = s;
    __syncthreads();
    for (int off = 1; off < 1024; off <<= 1) {
        int v = (t >= off) ? sums[t - off] : 0;
        __syncthreads();
        sums[t] += v;
        __syncthreads();
    }
    int run = (t == 0) ? 0 : sums[t - 1];
    for (int i = lo; i < hi; ++i) {
        rowptr[i] = run;
        fill[i] = run;
        run += deg[i];
    }
    if (t == 1023) rowptr[N] = sums[1023];
}

__global__ __launch_bounds__(256) void scatter_kernel(const int* __restrict__ ei,
                                                      int* __restrict__ fill,
                                                      int* __restrict__ col, int E, int N) {
    int i = blockIdx.x * 256 + threadIdx.x;
    int total = E + N;
    if (i >= total) return;
    int s, d;
    if (i < E) { s = ei[i]; d = ei[E + i]; }
    else       { s = i - E; d = s; }
    int pos = atomicAdd(&fill[d], 1);
    col[pos] = s;
}

// ---------------- fp32 tiled GEMM with fused attention-coefficient epilogue ----------------
// C[M,Ncol] = A[M,K] @ B[K,Ncol]; 64x64 tile per 256-thread block, 4x4 micro-tile.
// BF16C: store C as bf16 (gather operand); else fp32. Epilogue computes es/ed for
// this head tile from the fp32 accumulators (full precision).
template <int H, int BF16C>
__global__ __launch_bounds__(256) void gemm_attn_kernel(const float* __restrict__ A,
                                                        const float* __restrict__ B,
                                                        float* __restrict__ Cf,
                                                        unsigned short* __restrict__ Cb,
                                                        const float* __restrict__ as_,
                                                        const float* __restrict__ ad_,
                                                        float* __restrict__ es,
                                                        float* __restrict__ ed,
                                                        int M, int K, int Ncol) {
    __shared__ __align__(16) float As[16][64];  // [k][m]
    __shared__ __align__(16) float Bs[16][64];  // [k][n]
    int tid = threadIdx.x;
    int bm = blockIdx.x * 64;
    int bn = blockIdx.y * 64;
    int tm = (tid >> 4) * 4;
    int tn = (tid & 15) * 4;
    float acc[4][4] = {};
    int ar  = tid >> 2;        // 0..63 row of A tile
    int akk = (tid & 3) * 4;   // 0,4,8,12
    int brr = tid >> 4;        // 0..15 row of B tile
    int bcc = (tid & 15) * 4;
    for (int k0 = 0; k0 < K; k0 += 16) {
        int grow = bm + ar;
        float4 av;
        if (grow < M) av = *reinterpret_cast<const float4*>(A + (size_t)grow * K + k0 + akk);
        else          av = make_float4(0.f, 0.f, 0.f, 0.f);
        As[akk + 0][ar] = av.x;
        As[akk + 1][ar] = av.y;
        As[akk + 2][ar] = av.z;
        As[akk + 3][ar] = av.w;
        float4 bv = *reinterpret_cast<const float4*>(B + (size_t)(k0 + brr) * Ncol + bn + bcc);
        *reinterpret_cast<float4*>(&Bs[brr][bcc]) = bv;
        __syncthreads();
        #pragma unroll
        for (int kk = 0; kk < 16; ++kk) {
            float4 a4 = *reinterpret_cast<const float4*>(&As[kk][tm]);
            float4 b4 = *reinterpret_cast<const float4*>(&Bs[kk][tn]);
            float a[4] = {a4.x, a4.y, a4.z, a4.w};
            float b[4] = {b4.x, b4.y, b4.z, b4.w};
            #pragma unroll
            for (int i = 0; i < 4; ++i)
                #pragma unroll
                for (int j = 0; j < 4; ++j) acc[i][j] += a[i] * b[j];
        }
        __syncthreads();
    }
    #pragma unroll
    for (int i = 0; i < 4; ++i) {
        int gr = bm + tm + i;
        if (gr < M) {
            if constexpr (BF16C) {
                ushort4 r;
                r.x = f2bf(acc[i][0]); r.y = f2bf(acc[i][1]);
                r.z = f2bf(acc[i][2]); r.w = f2bf(acc[i][3]);
                *reinterpret_cast<ushort4*>(Cb + (size_t)gr * Ncol + bn + tn) = r;
            } else {
                float4 r = make_float4(acc[i][0], acc[i][1], acc[i][2], acc[i][3]);
                *reinterpret_cast<float4*>(Cf + (size_t)gr * Ncol + bn + tn) = r;
            }
        }
    }
    // ---- fused es/ed epilogue ----
    int hy = blockIdx.y;  // head index (Ncol == H*64)
    float4 asv = *reinterpret_cast<const float4*>(as_ + (size_t)hy * 64 + tn);
    float4 adv = *reinterpret_cast<const float4*>(ad_ + (size_t)hy * 64 + tn);
    float sv[4], dv[4];
    #pragma unroll
    for (int i = 0; i < 4; ++i) {
        sv[i] = acc[i][0] * asv.x + acc[i][1] * asv.y + acc[i][2] * asv.z + acc[i][3] * asv.w;
        dv[i] = acc[i][0] * adv.x + acc[i][1] * adv.y + acc[i][2] * adv.z + acc[i][3] * adv.w;
    }
    #pragma unroll
    for (int off = 1; off < 16; off <<= 1) {
        #pragma unroll
        for (int i = 0; i < 4; ++i) {
            sv[i] += __shfl_xor(sv[i], off, 64);
            dv[i] += __shfl_xor(dv[i], off, 64);
        }
    }
    if ((tid & 15) == 0) {
        #pragma unroll
        for (int i = 0; i < 4; ++i) {
            int gr = bm + tm + i;
            if (gr < M) {
                es[(size_t)gr * H + hy] = sv[i];
                ed[(size_t)gr * H + hy] = dv[i];
            }
        }
    }
}

__device__ __forceinline__ float lrelu02(float x) { return x > 0.f ? x : 0.2f * x; }
__device__ __forceinline__ float eluf(float x)    { return x > 0.f ? x : expm1f(x); }

// ---------------- fused per-dst aggregation, H=4, bf16 gather operand ----------------
// One 64-lane wave per destination node, 4 nodes per block. Per 64-edge chunk:
// coalesced col/es loads -> softmax weights in LDS -> gather loop over bf16 h
// (8 B/lane/edge) with addresses known up front. Unnormalized accumulate;
// single divide at the end. plds padded to 68 to break the 4-way bank conflict.
template <int ACT>
__global__ __launch_bounds__(256) void agg4_kernel(const unsigned short* __restrict__ hb,
                                                   const float* __restrict__ es,
                                                   const float* __restrict__ ed,
                                                   const int* __restrict__ rowptr,
                                                   const int* __restrict__ col,
                                                   const float* __restrict__ bias,
                                                   float* __restrict__ out, int N) {
    __shared__ int   slds[4][64];
    __shared__ float plds[4][4][68];   // +4 pad: heads land in different banks
    int sub  = threadIdx.x >> 6;
    int lane = threadIdx.x & 63;
    int node = blockIdx.x * 4 + sub;
    if (node >= N) return;
    int s = rowptr[node], t = rowptr[node + 1];

    float edv[4];
    #pragma unroll
    for (int h = 0; h < 4; ++h) edv[h] = ed[(size_t)node * 4 + h];

    // phase A: per-head max over incoming edges
    float mx[4] = {-3.0e38f, -3.0e38f, -3.0e38f, -3.0e38f};
    for (int base = s; base < t; base += 64) {
        int j = base + lane;
        if (j < t) {
            int sc = col[j];
            float4 e4 = *reinterpret_cast<const float4*>(es + (size_t)sc * 4);
            mx[0] = fmaxf(mx[0], lrelu02(e4.x + edv[0]));
            mx[1] = fmaxf(mx[1], lrelu02(e4.y + edv[1]));
            mx[2] = fmaxf(mx[2], lrelu02(e4.z + edv[2]));
            mx[3] = fmaxf(mx[3], lrelu02(e4.w + edv[3]));
        }
    }
    #pragma unroll
    for (int off = 32; off; off >>= 1)
        #pragma unroll
        for (int h = 0; h < 4; ++h) mx[h] = fmaxf(mx[h], __shfl_xor(mx[h], off, 64));

    // phase B: weights -> LDS, unnormalized gather-accumulate
    float den[4] = {0.f, 0.f, 0.f, 0.f};
    int hh = lane >> 4;  // this lane's head (4 dims per lane)
    float4 acc = make_float4(0.f, 0.f, 0.f, 0.f);
    for (int base = s; base < t; base += 64) {
        int j = base + lane;
        int m = t - base; if (m > 64) m = 64;
        int sc = 0;
        float p[4] = {0.f, 0.f, 0.f, 0.f};
        if (j < t) {
            sc = col[j];
            float4 e4 = *reinterpret_cast<const float4*>(es + (size_t)sc * 4);
            p[0] = __expf(lrelu02(e4.x + edv[0]) - mx[0]);
            p[1] = __expf(lrelu02(e4.y + edv[1]) - mx[1]);
            p[2] = __expf(lrelu02(e4.z + edv[2]) - mx[2]);
            p[3] = __expf(lrelu02(e4.w + edv[3]) - mx[3]);
        }
        slds[sub][lane] = sc;
        #pragma unroll
        for (int h = 0; h < 4; ++h) {
            den[h] += p[h];
            plds[sub][h][lane] = p[h];
        }
        #pragma unroll 4
        for (int jj = 0; jj < m; ++jj) {
            int scj = slds[sub][jj];
            float a = plds[sub][hh][jj];
            uint2 u = *reinterpret_cast<const uint2*>(hb + (size_t)scj * 256 + lane * 4);
            acc.x += __uint_as_float(u.x << 16)          * a;
            acc.y += __uint_as_float(u.x & 0xffff0000u)  * a;
            acc.z += __uint_as_float(u.y << 16)          * a;
            acc.w += __uint_as_float(u.y & 0xffff0000u)  * a;
        }
    }
    #pragma unroll
    for (int off = 32; off; off >>= 1)
        #pragma unroll
        for (int h = 0; h < 4; ++h) den[h] += __shfl_xor(den[h], off, 64);
    float inv = 1.f / den[hh];
    float4 bv = *reinterpret_cast<const float4*>(bias + lane * 4);
    float4 r;
    r.x = acc.x * inv + bv.x;
    r.y = acc.y * inv + bv.y;
    r.z = acc.z * inv + bv.z;
    r.w = acc.w * inv + bv.w;
    if (ACT) { r.x = eluf(r.x); r.y = eluf(r.y); r.z = eluf(r.z); r.w = eluf(r.w); }
    *reinterpret_cast<float4*>(out + (size_t)node * 256 + lane * 4) = r;
}

// ---------------- fused per-dst aggregation, H=1, fp32 gather (final layer) ----------------
__global__ __launch_bounds__(256) void agg1_kernel(const float* __restrict__ hbuf,
                                                   const float* __restrict__ es,
                                                   const float* __restrict__ ed,
                                                   const int* __restrict__ rowptr,
                                                   const int* __restrict__ col,
                                                   const float* __restrict__ bias,
                                                   float* __restrict__ out, int N) {
    __shared__ int   slds[4][64];
    __shared__ float plds[4][64];
    int sub  = threadIdx.x >> 6;
    int lane = threadIdx.x & 63;
    int node = blockIdx.x * 4 + sub;
    if (node >= N) return;
    int s = rowptr[node], t = rowptr[node + 1];
    float edv = ed[node];

    float mx = -3.0e38f;
    for (int base = s; base < t; base += 64) {
        int j = base + lane;
        if (j < t) mx = fmaxf(mx, lrelu02(es[col[j]] + edv));
    }
    #pragma unroll
    for (int off = 32; off; off >>= 1) mx = fmaxf(mx, __shfl_xor(mx, off, 64));

    float den = 0.f, acc = 0.f;
    for (int base = s; base < t; base += 64) {
        int j = base + lane;
        int m = t - base; if (m > 64) m = 64;
        int sc = 0;
        float p0 = 0.f;
        if (j < t) {
            sc = col[j];
            p0 = __expf(lrelu02(es[sc] + edv) - mx);
        }
        slds[sub][lane] = sc;
        plds[sub][lane] = p0;
        den += p0;
        #pragma unroll 4
        for (int jj = 0; jj < m; ++jj) {
            int scj = slds[sub][jj];
            float a = plds[sub][jj];
            acc += hbuf[(size_t)scj * 64 + lane] * a;
        }
    }
    #pragma unroll
    for (int off = 32; off; off >>= 1) den += __shfl_xor(den, off, 64);
    out[(size_t)node * 64 + lane] = acc * (1.f / den) + bias[lane];
}

// ---------------- graph mean ----------------
__global__ __launch_bounds__(256) void gmean_partial(const float* __restrict__ ne,
                                                     float* __restrict__ part, int N) {
    int d = threadIdx.x & 63, sub = threadIdx.x >> 6;
    int start = blockIdx.x * 4 + sub;
    float s = 0.f;
    for (int n = start; n < N; n += gridDim.x * 4) s += ne[(size_t)n * 64 + d];
    __shared__ float ls[256];
    ls[threadIdx.x] = s;
    __syncthreads();
    if (threadIdx.x < 64) {
        float v = ls[threadIdx.x] + ls[threadIdx.x + 64] + ls[threadIdx.x + 128] + ls[threadIdx.x + 192];
        part[blockIdx.x * 64 + d] = v;
    }
}

__global__ __launch_bounds__(64) void gmean_final(const float* __restrict__ part,
                                                  float* __restrict__ gout, int nblk, float invN) {
    int d = threadIdx.x;
    float s = 0.f;
    for (int b = 0; b < nblk; ++b) s += part[b * 64 + d];
    gout[d] = s * invN;
}

extern "C" void kernel_launch(void* const* d_in, const int* in_sizes, int n_in,
                              void* d_out, int out_size, void* d_ws, size_t ws_size,
                              hipStream_t stream) {
    const float* x   = (const float*)d_in[0];
    const int*   ei  = (const int*)d_in[1];
    const float* W1  = (const float*)d_in[2];
    const float* a1s = (const float*)d_in[3];
    const float* a1d = (const float*)d_in[4];
    const float* b1  = (const float*)d_in[5];
    const float* W2  = (const float*)d_in[6];
    const float* a2s = (const float*)d_in[7];
    const float* a2d = (const float*)d_in[8];
    const float* b2  = (const float*)d_in[9];
    const float* W3  = (const float*)d_in[10];
    const float* a3s = (const float*)d_in[11];
    const float* a3d = (const float*)d_in[12];
    const float* b3  = (const float*)d_in[13];
    float* out = (float*)d_out;

    const int N = NNODES;
    const int E = in_sizes[1] / 2;  // 800000

    // workspace carve (16B alignment maintained)
    char* w = (char*)d_ws;
    unsigned short* Hb = (unsigned short*)w; w += (size_t)N * 256 * 2;  // bf16 h (layers 1-2)
    float* B0 = (float*)w; w += (size_t)N * 256 * 4;   // fp32 buffer (gemm3 C / agg out)
    float* B1 = (float*)w; w += (size_t)N * 256 * 4;   // agg out ping-pong
    float* es = (float*)w; w += (size_t)N * 4 * 4;
    float* ed = (float*)w; w += (size_t)N * 4 * 4;
    int* deg    = (int*)w; w += (size_t)N * 4;
    int* rowptr = (int*)w; w += (size_t)(N + 2) * 4;
    int* fill   = (int*)w; w += (size_t)N * 4;
    int* col    = (int*)w; w += (size_t)(E + N) * 4;
    float* part = (float*)w; w += 128 * 64 * 4;
    (void)ws_size; (void)n_in; (void)out_size;

    // ---- CSR build (dst-sorted adjacency incl. self-loops) ----
    deg_init_kernel<<<(N + 255) / 256, 256, 0, stream>>>(deg, N);
    deg_count_kernel<<<(E + 255) / 256, 256, 0, stream>>>(ei, deg, E);
    scan_kernel<<<1, 1024, 0, stream>>>(deg, rowptr, fill, N);
    scatter_kernel<<<(E + N + 255) / 256, 256, 0, stream>>>(ei, fill, col, E, N);

    // ---- Layer 1: x[N,16] @ W1[16,256], H=4, C->bf16 ----
    gemm_attn_kernel<4, 1><<<dim3((N + 63) / 64, 4), 256, 0, stream>>>(
        x, W1, nullptr, Hb, a1s, a1d, es, ed, N, 16, 256);
    agg4_kernel<1><<<(N + 3) / 4, 256, 0, stream>>>(Hb, es, ed, rowptr, col, b1, B1, N);

    // ---- Layer 2: B1[N,256] @ W2[256,256], H=4, C->bf16 ----
    gemm_attn_kernel<4, 1><<<dim3((N + 63) / 64, 4), 256, 0, stream>>>(
        B1, W2, nullptr, Hb, a2s, a2d, es, ed, N, 256, 256);
    agg4_kernel<1><<<(N + 3) / 4, 256, 0, stream>>>(Hb, es, ed, rowptr, col, b2, B0, N);

    // ---- Layer 3: B0[N,256] @ W3[256,64], H=1, fp32 C (feeds output directly) ----
    gemm_attn_kernel<1, 0><<<dim3((N + 63) / 64, 1), 256, 0, stream>>>(
        B0, W3, B1, nullptr, a3s, a3d, es, ed, N, 256, 64);
    agg1_kernel<<<(N + 3) / 4, 256, 0, stream>>>(B1, es, ed, rowptr, col, b3, out, N);

    // ---- graph mean over nodes ----
    gmean_partial<<<128, 256, 0, stream>>>(out, part, N);
    gmean_final<<<1, 64, 0, stream>>>(part, out + (size_t)N * 64, 128, 1.0f / N);
}

// Round 4
// 566.829 us; speedup vs baseline: 1.5881x; 1.1731x over previous
//
#include <hip/hip_runtime.h>
#include <math.h>

#define NNODES 50000

__device__ __forceinline__ unsigned short f2bf(float f) {
    unsigned u = __float_as_uint(f);
    u += 0x7fffu + ((u >> 16) & 1);   // RTN-even
    return (unsigned short)(u >> 16);
}

// ---------------- CSR build ----------------
__global__ __launch_bounds__(256) void deg_init_kernel(int* __restrict__ deg, int N) {
    int i = blockIdx.x * 256 + threadIdx.x;
    if (i < N) deg[i] = 1;  // self-loop
}

__global__ __launch_bounds__(256) void deg_count_kernel(const int* __restrict__ ei,
                                                        int* __restrict__ deg, int E) {
    int i = blockIdx.x * 256 + threadIdx.x;
    if (i < E) atomicAdd(&deg[ei[E + i]], 1);
}

// ---- 3-phase multi-block exclusive scan over deg[N] -> rowptr/fill, rowptr[N]=total ----
__global__ __launch_bounds__(256) void scan_partial_kernel(const int* __restrict__ deg,
                                                           int* __restrict__ bsum, int N) {
    __shared__ int ls[256];
    int t = threadIdx.x;
    int i = blockIdx.x * 256 + t;
    ls[t] = (i < N) ? deg[i] : 0;
    __syncthreads();
    #pragma unroll
    for (int off = 128; off; off >>= 1) {
        if (t < off) ls[t] += ls[t + off];
        __syncthreads();
    }
    if (t == 0) bsum[blockIdx.x] = ls[0];
}

__global__ __launch_bounds__(256) void scan_blocks_kernel(const int* __restrict__ bsum,
                                                          int* __restrict__ boff,
                                                          int* __restrict__ rowptrN, int nblk) {
    __shared__ int ls[256];
    int t = threadIdx.x;
    int v = (t < nblk) ? bsum[t] : 0;
    ls[t] = v;
    __syncthreads();
    for (int off = 1; off < 256; off <<= 1) {
        int u = (t >= off) ? ls[t - off] : 0;
        __syncthreads();
        ls[t] += u;
        __syncthreads();
    }
    if (t < nblk) boff[t] = ls[t] - v;
    if (t == 255) *rowptrN = ls[255];
}

__global__ __launch_bounds__(256) void scan_final_kernel(const int* __restrict__ deg,
                                                         const int* __restrict__ boff,
                                                         int* __restrict__ rowptr,
                                                         int* __restrict__ fill, int N) {
    __shared__ int ls[256];
    int t = threadIdx.x;
    int i = blockIdx.x * 256 + t;
    int v = (i < N) ? deg[i] : 0;
    ls[t] = v;
    __syncthreads();
    for (int off = 1; off < 256; off <<= 1) {
        int u = (t >= off) ? ls[t - off] : 0;
        __syncthreads();
        ls[t] += u;
        __syncthreads();
    }
    if (i < N) {
        int e = boff[blockIdx.x] + ls[t] - v;
        rowptr[i] = e;
        fill[i] = e;
    }
}

__global__ __launch_bounds__(256) void scatter_kernel(const int* __restrict__ ei,
                                                      int* __restrict__ fill,
                                                      int* __restrict__ col, int E, int N) {
    int i = blockIdx.x * 256 + threadIdx.x;
    int total = E + N;
    if (i >= total) return;
    int s, d;
    if (i < E) { s = ei[i]; d = ei[E + i]; }
    else       { s = i - E; d = s; }
    int pos = atomicAdd(&fill[d], 1);
    col[pos] = s;
}

// ---------------- fp32 tiled GEMM with fused attention-coefficient epilogue ----------------
// C[M,Ncol] = A[M,K] @ B[K,Ncol]; 64x64 tile per 256-thread block, 4x4 micro-tile.
// BF16C: store C as bf16 (gather operand); else fp32. Epilogue computes es/ed for
// this head tile from the fp32 accumulators (full precision).
template <int H, int BF16C>
__global__ __launch_bounds__(256) void gemm_attn_kernel(const float* __restrict__ A,
                                                        const float* __restrict__ B,
                                                        float* __restrict__ Cf,
                                                        unsigned short* __restrict__ Cb,
                                                        const float* __restrict__ as_,
                                                        const float* __restrict__ ad_,
                                                        float* __restrict__ es,
                                                        float* __restrict__ ed,
                                                        int M, int K, int Ncol) {
    __shared__ __align__(16) float As[16][64];  // [k][m]
    __shared__ __align__(16) float Bs[16][64];  // [k][n]
    int tid = threadIdx.x;
    int bm = blockIdx.x * 64;
    int bn = blockIdx.y * 64;
    int tm = (tid >> 4) * 4;
    int tn = (tid & 15) * 4;
    float acc[4][4] = {};
    int ar  = tid >> 2;        // 0..63 row of A tile
    int akk = (tid & 3) * 4;   // 0,4,8,12
    int brr = tid >> 4;        // 0..15 row of B tile
    int bcc = (tid & 15) * 4;
    for (int k0 = 0; k0 < K; k0 += 16) {
        int grow = bm + ar;
        float4 av;
        if (grow < M) av = *reinterpret_cast<const float4*>(A + (size_t)grow * K + k0 + akk);
        else          av = make_float4(0.f, 0.f, 0.f, 0.f);
        As[akk + 0][ar] = av.x;
        As[akk + 1][ar] = av.y;
        As[akk + 2][ar] = av.z;
        As[akk + 3][ar] = av.w;
        float4 bv = *reinterpret_cast<const float4*>(B + (size_t)(k0 + brr) * Ncol + bn + bcc);
        *reinterpret_cast<float4*>(&Bs[brr][bcc]) = bv;
        __syncthreads();
        #pragma unroll
        for (int kk = 0; kk < 16; ++kk) {
            float4 a4 = *reinterpret_cast<const float4*>(&As[kk][tm]);
            float4 b4 = *reinterpret_cast<const float4*>(&Bs[kk][tn]);
            float a[4] = {a4.x, a4.y, a4.z, a4.w};
            float b[4] = {b4.x, b4.y, b4.z, b4.w};
            #pragma unroll
            for (int i = 0; i < 4; ++i)
                #pragma unroll
                for (int j = 0; j < 4; ++j) acc[i][j] += a[i] * b[j];
        }
        __syncthreads();
    }
    #pragma unroll
    for (int i = 0; i < 4; ++i) {
        int gr = bm + tm + i;
        if (gr < M) {
            if constexpr (BF16C) {
                ushort4 r;
                r.x = f2bf(acc[i][0]); r.y = f2bf(acc[i][1]);
                r.z = f2bf(acc[i][2]); r.w = f2bf(acc[i][3]);
                *reinterpret_cast<ushort4*>(Cb + (size_t)gr * Ncol + bn + tn) = r;
            } else {
                float4 r = make_float4(acc[i][0], acc[i][1], acc[i][2], acc[i][3]);
                *reinterpret_cast<float4*>(Cf + (size_t)gr * Ncol + bn + tn) = r;
            }
        }
    }
    // ---- fused es/ed epilogue ----
    int hy = blockIdx.y;  // head index (Ncol == H*64)
    float4 asv = *reinterpret_cast<const float4*>(as_ + (size_t)hy * 64 + tn);
    float4 adv = *reinterpret_cast<const float4*>(ad_ + (size_t)hy * 64 + tn);
    float sv[4], dv[4];
    #pragma unroll
    for (int i = 0; i < 4; ++i) {
        sv[i] = acc[i][0] * asv.x + acc[i][1] * asv.y + acc[i][2] * asv.z + acc[i][3] * asv.w;
        dv[i] = acc[i][0] * adv.x + acc[i][1] * adv.y + acc[i][2] * adv.z + acc[i][3] * adv.w;
    }
    #pragma unroll
    for (int off = 1; off < 16; off <<= 1) {
        #pragma unroll
        for (int i = 0; i < 4; ++i) {
            sv[i] += __shfl_xor(sv[i], off, 64);
            dv[i] += __shfl_xor(dv[i], off, 64);
        }
    }
    if ((tid & 15) == 0) {
        #pragma unroll
        for (int i = 0; i < 4; ++i) {
            int gr = bm + tm + i;
            if (gr < M) {
                es[(size_t)gr * H + hy] = sv[i];
                ed[(size_t)gr * H + hy] = dv[i];
            }
        }
    }
}

__device__ __forceinline__ float lrelu02(float x) { return x > 0.f ? x : 0.2f * x; }
__device__ __forceinline__ float eluf(float x)    { return x > 0.f ? x : expm1f(x); }

// ---------------- fused per-dst aggregation, H=4, bf16 gather operand ----------------
template <int ACT>
__global__ __launch_bounds__(256) void agg4_kernel(const unsigned short* __restrict__ hb,
                                                   const float* __restrict__ es,
                                                   const float* __restrict__ ed,
                                                   const int* __restrict__ rowptr,
                                                   const int* __restrict__ col,
                                                   const float* __restrict__ bias,
                                                   float* __restrict__ out, int N) {
    __shared__ int   slds[4][64];
    __shared__ float plds[4][4][68];   // +4 pad: heads land in different banks
    int sub  = threadIdx.x >> 6;
    int lane = threadIdx.x & 63;
    int node = blockIdx.x * 4 + sub;
    if (node >= N) return;
    int s = rowptr[node], t = rowptr[node + 1];

    float edv[4];
    #pragma unroll
    for (int h = 0; h < 4; ++h) edv[h] = ed[(size_t)node * 4 + h];

    // phase A: per-head max over incoming edges
    float mx[4] = {-3.0e38f, -3.0e38f, -3.0e38f, -3.0e38f};
    for (int base = s; base < t; base += 64) {
        int j = base + lane;
        if (j < t) {
            int sc = col[j];
            float4 e4 = *reinterpret_cast<const float4*>(es + (size_t)sc * 4);
            mx[0] = fmaxf(mx[0], lrelu02(e4.x + edv[0]));
            mx[1] = fmaxf(mx[1], lrelu02(e4.y + edv[1]));
            mx[2] = fmaxf(mx[2], lrelu02(e4.z + edv[2]));
            mx[3] = fmaxf(mx[3], lrelu02(e4.w + edv[3]));
        }
    }
    #pragma unroll
    for (int off = 32; off; off >>= 1)
        #pragma unroll
        for (int h = 0; h < 4; ++h) mx[h] = fmaxf(mx[h], __shfl_xor(mx[h], off, 64));

    // phase B: weights -> LDS, unnormalized gather-accumulate
    float den[4] = {0.f, 0.f, 0.f, 0.f};
    int hh = lane >> 4;  // this lane's head (4 dims per lane)
    float4 acc = make_float4(0.f, 0.f, 0.f, 0.f);
    for (int base = s; base < t; base += 64) {
        int j = base + lane;
        int m = t - base; if (m > 64) m = 64;
        int sc = 0;
        float p[4] = {0.f, 0.f, 0.f, 0.f};
        if (j < t) {
            sc = col[j];
            float4 e4 = *reinterpret_cast<const float4*>(es + (size_t)sc * 4);
            p[0] = __expf(lrelu02(e4.x + edv[0]) - mx[0]);
            p[1] = __expf(lrelu02(e4.y + edv[1]) - mx[1]);
            p[2] = __expf(lrelu02(e4.z + edv[2]) - mx[2]);
            p[3] = __expf(lrelu02(e4.w + edv[3]) - mx[3]);
        }
        slds[sub][lane] = sc;
        #pragma unroll
        for (int h = 0; h < 4; ++h) {
            den[h] += p[h];
            plds[sub][h][lane] = p[h];
        }
        #pragma unroll 4
        for (int jj = 0; jj < m; ++jj) {
            int scj = slds[sub][jj];
            float a = plds[sub][hh][jj];
            uint2 u = *reinterpret_cast<const uint2*>(hb + (size_t)scj * 256 + lane * 4);
            acc.x += __uint_as_float(u.x << 16)          * a;
            acc.y += __uint_as_float(u.x & 0xffff0000u)  * a;
            acc.z += __uint_as_float(u.y << 16)          * a;
            acc.w += __uint_as_float(u.y & 0xffff0000u)  * a;
        }
    }
    #pragma unroll
    for (int off = 32; off; off >>= 1)
        #pragma unroll
        for (int h = 0; h < 4; ++h) den[h] += __shfl_xor(den[h], off, 64);
    float inv = 1.f / den[hh];
    float4 bv = *reinterpret_cast<const float4*>(bias + lane * 4);
    float4 r;
    r.x = acc.x * inv + bv.x;
    r.y = acc.y * inv + bv.y;
    r.z = acc.z * inv + bv.z;
    r.w = acc.w * inv + bv.w;
    if (ACT) { r.x = eluf(r.x); r.y = eluf(r.y); r.z = eluf(r.z); r.w = eluf(r.w); }
    *reinterpret_cast<float4*>(out + (size_t)node * 256 + lane * 4) = r;
}

// ---------------- fused per-dst aggregation, H=1, fp32 gather (final layer) ----------------
__global__ __launch_bounds__(256) void agg1_kernel(const float* __restrict__ hbuf,
                                                   const float* __restrict__ es,
                                                   const float* __restrict__ ed,
                                                   const int* __restrict__ rowptr,
                                                   const int* __restrict__ col,
                                                   const float* __restrict__ bias,
                                                   float* __restrict__ out, int N) {
    __shared__ int   slds[4][64];
    __shared__ float plds[4][64];
    int sub  = threadIdx.x >> 6;
    int lane = threadIdx.x & 63;
    int node = blockIdx.x * 4 + sub;
    if (node >= N) return;
    int s = rowptr[node], t = rowptr[node + 1];
    float edv = ed[node];

    float mx = -3.0e38f;
    for (int base = s; base < t; base += 64) {
        int j = base + lane;
        if (j < t) mx = fmaxf(mx, lrelu02(es[col[j]] + edv));
    }
    #pragma unroll
    for (int off = 32; off; off >>= 1) mx = fmaxf(mx, __shfl_xor(mx, off, 64));

    float den = 0.f, acc = 0.f;
    for (int base = s; base < t; base += 64) {
        int j = base + lane;
        int m = t - base; if (m > 64) m = 64;
        int sc = 0;
        float p0 = 0.f;
        if (j < t) {
            sc = col[j];
            p0 = __expf(lrelu02(es[sc] + edv) - mx);
        }
        slds[sub][lane] = sc;
        plds[sub][lane] = p0;
        den += p0;
        #pragma unroll 4
        for (int jj = 0; jj < m; ++jj) {
            int scj = slds[sub][jj];
            float a = plds[sub][jj];
            acc += hbuf[(size_t)scj * 64 + lane] * a;
        }
    }
    #pragma unroll
    for (int off = 32; off; off >>= 1) den += __shfl_xor(den, off, 64);
    out[(size_t)node * 64 + lane] = acc * (1.f / den) + bias[lane];
}

// ---------------- graph mean ----------------
__global__ __launch_bounds__(256) void gmean_partial(const float* __restrict__ ne,
                                                     float* __restrict__ part, int N) {
    int d = threadIdx.x & 63, sub = threadIdx.x >> 6;
    int start = blockIdx.x * 4 + sub;
    float s = 0.f;
    for (int n = start; n < N; n += gridDim.x * 4) s += ne[(size_t)n * 64 + d];
    __shared__ float ls[256];
    ls[threadIdx.x] = s;
    __syncthreads();
    if (threadIdx.x < 64) {
        float v = ls[threadIdx.x] + ls[threadIdx.x + 64] + ls[threadIdx.x + 128] + ls[threadIdx.x + 192];
        part[blockIdx.x * 64 + d] = v;
    }
}

__global__ __launch_bounds__(64) void gmean_final(const float* __restrict__ part,
                                                  float* __restrict__ gout, int nblk, float invN) {
    int d = threadIdx.x;
    float s = 0.f;
    for (int b = 0; b < nblk; ++b) s += part[b * 64 + d];
    gout[d] = s * invN;
}

extern "C" void kernel_launch(void* const* d_in, const int* in_sizes, int n_in,
                              void* d_out, int out_size, void* d_ws, size_t ws_size,
                              hipStream_t stream) {
    const float* x   = (const float*)d_in[0];
    const int*   ei  = (const int*)d_in[1];
    const float* W1  = (const float*)d_in[2];
    const float* a1s = (const float*)d_in[3];
    const float* a1d = (const float*)d_in[4];
    const float* b1  = (const float*)d_in[5];
    const float* W2  = (const float*)d_in[6];
    const float* a2s = (const float*)d_in[7];
    const float* a2d = (const float*)d_in[8];
    const float* b2  = (const float*)d_in[9];
    const float* W3  = (const float*)d_in[10];
    const float* a3s = (const float*)d_in[11];
    const float* a3d = (const float*)d_in[12];
    const float* b3  = (const float*)d_in[13];
    float* out = (float*)d_out;

    const int N = NNODES;
    const int E = in_sizes[1] / 2;  // 800000
    const int NB = (N + 255) / 256; // scan blocks (196)

    // workspace carve (16B alignment maintained)
    char* w = (char*)d_ws;
    unsigned short* Hb = (unsigned short*)w; w += (size_t)N * 256 * 2;  // bf16 h (layers 1-2)
    float* B0 = (float*)w; w += (size_t)N * 256 * 4;   // fp32 buffer (gemm3 C / agg out)
    float* B1 = (float*)w; w += (size_t)N * 256 * 4;   // agg out ping-pong
    float* es = (float*)w; w += (size_t)N * 4 * 4;
    float* ed = (float*)w; w += (size_t)N * 4 * 4;
    int* deg    = (int*)w; w += (size_t)N * 4;
    int* rowptr = (int*)w; w += (size_t)(N + 2) * 4;
    int* fill   = (int*)w; w += (size_t)N * 4;
    int* col    = (int*)w; w += (size_t)(E + N) * 4;
    int* bsum   = (int*)w; w += 256 * 4;
    int* boff   = (int*)w; w += 256 * 4;
    float* part = (float*)w; w += 128 * 64 * 4;
    (void)ws_size; (void)n_in; (void)out_size;

    // ---- CSR build (dst-sorted adjacency incl. self-loops) ----
    deg_init_kernel<<<NB, 256, 0, stream>>>(deg, N);
    deg_count_kernel<<<(E + 255) / 256, 256, 0, stream>>>(ei, deg, E);
    scan_partial_kernel<<<NB, 256, 0, stream>>>(deg, bsum, N);
    scan_blocks_kernel<<<1, 256, 0, stream>>>(bsum, boff, rowptr + N, NB);
    scan_final_kernel<<<NB, 256, 0, stream>>>(deg, boff, rowptr, fill, N);
    scatter_kernel<<<(E + N + 255) / 256, 256, 0, stream>>>(ei, fill, col, E, N);

    // ---- Layer 1: x[N,16] @ W1[16,256], H=4, C->bf16 ----
    gemm_attn_kernel<4, 1><<<dim3((N + 63) / 64, 4), 256, 0, stream>>>(
        x, W1, nullptr, Hb, a1s, a1d, es, ed, N, 16, 256);
    agg4_kernel<1><<<(N + 3) / 4, 256, 0, stream>>>(Hb, es, ed, rowptr, col, b1, B1, N);

    // ---- Layer 2: B1[N,256] @ W2[256,256], H=4, C->bf16 ----
    gemm_attn_kernel<4, 1><<<dim3((N + 63) / 64, 4), 256, 0, stream>>>(
        B1, W2, nullptr, Hb, a2s, a2d, es, ed, N, 256, 256);
    agg4_kernel<1><<<(N + 3) / 4, 256, 0, stream>>>(Hb, es, ed, rowptr, col, b2, B0, N);

    // ---- Layer 3: B0[N,256] @ W3[256,64], H=1, fp32 C (feeds output directly) ----
    gemm_attn_kernel<1, 0><<<dim3((N + 63) / 64, 1), 256, 0, stream>>>(
        B0, W3, B1, nullptr, a3s, a3d, es, ed, N, 256, 64);
    agg1_kernel<<<(N + 3) / 4, 256, 0, stream>>>(B1, es, ed, rowptr, col, b3, out, N);

    // ---- graph mean over nodes ----
    gmean_partial<<<128, 256, 0, stream>>>(out, part, N);
    gmean_final<<<1, 64, 0, stream>>>(part, out + (size_t)N * 64, 128, 1.0f / N);
}

// Round 5
// 523.247 us; speedup vs baseline: 1.7204x; 1.0833x over previous
//
#include <hip/hip_runtime.h>
#include <math.h>

#define NNODES 50000

typedef __attribute__((ext_vector_type(8))) short short8;   // 8 bf16 (4 VGPRs)
typedef __attribute__((ext_vector_type(4))) float f32x4;    // MFMA accumulator

__device__ __forceinline__ unsigned short f2bf(float f) {
    unsigned u = __float_as_uint(f);
    u += 0x7fffu + ((u >> 16) & 1);   // RTN-even
    return (unsigned short)(u >> 16);
}
__device__ __forceinline__ float bf2f(unsigned short h) {
    return __uint_as_float(((unsigned)h) << 16);
}

// ---------------- CSR build ----------------
__global__ __launch_bounds__(256) void deg_init_kernel(int* __restrict__ deg, int N) {
    int i = blockIdx.x * 256 + threadIdx.x;
    if (i < N) deg[i] = 1;  // self-loop
}

__global__ __launch_bounds__(256) void deg_count_kernel(const int* __restrict__ ei,
                                                        int* __restrict__ deg, int E) {
    int i = blockIdx.x * 256 + threadIdx.x;
    if (i < E) atomicAdd(&deg[ei[E + i]], 1);
}

// ---- 3-phase multi-block exclusive scan over deg[N] -> rowptr/fill, rowptr[N]=total ----
__global__ __launch_bounds__(256) void scan_partial_kernel(const int* __restrict__ deg,
                                                           int* __restrict__ bsum, int N) {
    __shared__ int ls[256];
    int t = threadIdx.x;
    int i = blockIdx.x * 256 + t;
    ls[t] = (i < N) ? deg[i] : 0;
    __syncthreads();
    #pragma unroll
    for (int off = 128; off; off >>= 1) {
        if (t < off) ls[t] += ls[t + off];
        __syncthreads();
    }
    if (t == 0) bsum[blockIdx.x] = ls[0];
}

__global__ __launch_bounds__(256) void scan_blocks_kernel(const int* __restrict__ bsum,
                                                          int* __restrict__ boff,
                                                          int* __restrict__ rowptrN, int nblk) {
    __shared__ int ls[256];
    int t = threadIdx.x;
    int v = (t < nblk) ? bsum[t] : 0;
    ls[t] = v;
    __syncthreads();
    for (int off = 1; off < 256; off <<= 1) {
        int u = (t >= off) ? ls[t - off] : 0;
        __syncthreads();
        ls[t] += u;
        __syncthreads();
    }
    if (t < nblk) boff[t] = ls[t] - v;
    if (t == 255) *rowptrN = ls[255];
}

__global__ __launch_bounds__(256) void scan_final_kernel(const int* __restrict__ deg,
                                                         const int* __restrict__ boff,
                                                         int* __restrict__ rowptr,
                                                         int* __restrict__ fill, int N) {
    __shared__ int ls[256];
    int t = threadIdx.x;
    int i = blockIdx.x * 256 + t;
    int v = (i < N) ? deg[i] : 0;
    ls[t] = v;
    __syncthreads();
    for (int off = 1; off < 256; off <<= 1) {
        int u = (t >= off) ? ls[t - off] : 0;
        __syncthreads();
        ls[t] += u;
        __syncthreads();
    }
    if (i < N) {
        int e = boff[blockIdx.x] + ls[t] - v;
        rowptr[i] = e;
        fill[i] = e;
    }
}

__global__ __launch_bounds__(256) void scatter_kernel(const int* __restrict__ ei,
                                                      int* __restrict__ fill,
                                                      int* __restrict__ col, int E, int N) {
    int i = blockIdx.x * 256 + threadIdx.x;
    int total = E + N;
    if (i >= total) return;
    int s, d;
    if (i < E) { s = ei[i]; d = ei[E + i]; }
    else       { s = i - E; d = s; }
    int pos = atomicAdd(&fill[d], 1);
    col[pos] = s;
}

// ---------------- W2 prep: transpose + split fp32 -> bf16 hi/lo in [n][k] layout ----------------
__global__ __launch_bounds__(256) void w2t_prep_kernel(const float* __restrict__ W,
                                                       unsigned short* __restrict__ Th,
                                                       unsigned short* __restrict__ Tl) {
    int k = blockIdx.x, n = threadIdx.x;   // 256 x 256
    float w = W[k * 256 + n];              // coalesced read
    unsigned short h = f2bf(w);
    unsigned short l = f2bf(w - bf2f(h));
    Th[n * 256 + k] = h;
    Tl[n * 256 + k] = l;
}

// ---------------- layer-2 GEMM: split-bf16 MFMA, fused es/ed epilogue ----------------
// C[M,256] = A[M,256] @ W2[256,256]; A fp32 (split in-kernel), W pre-split bf16 [n][k].
// Block: 256 thr = 4 waves (2x2), tile 128x128, wave-tile 64x64 = 4x4 MFMA 16x16x32 frags.
// acc = hiA*hiB + hiA*loB + loA*hiB (fp32-like accuracy, ~2^-16 rel).
// LDS k-stride padded to 40 (80 B = 20 banks -> conflict-free frag reads).
#define LDK 40
__global__ __launch_bounds__(256) void gemm2_mfma_kernel(const float* __restrict__ A,
                                                         const unsigned short* __restrict__ WTh,
                                                         const unsigned short* __restrict__ WTl,
                                                         unsigned short* __restrict__ Cb,
                                                         const float* __restrict__ as_,
                                                         const float* __restrict__ ad_,
                                                         float* __restrict__ es,
                                                         float* __restrict__ ed,
                                                         int M) {
    __shared__ __align__(16) unsigned short Ah[128][LDK], Al[128][LDK];
    __shared__ __align__(16) unsigned short Bh[128][LDK], Bl[128][LDK];
    int tid  = threadIdx.x;
    int lane = tid & 63, wave = tid >> 6;
    int wm = wave >> 1, wn = wave & 1;
    int bm = blockIdx.x * 128;
    int bn = blockIdx.y * 128;
    int c = lane & 15, q = lane >> 4;

    f32x4 acc[4][4] = {};  // [mt][nt], C/D: row = q*4+r, col = c

    for (int k0 = 0; k0 < 256; k0 += 32) {
        // stage A: 128 rows x 32 k, fp32 -> hi/lo bf16
        #pragma unroll
        for (int p = 0; p < 4; ++p) {
            int idx = p * 256 + tid;     // 0..1023
            int r   = idx >> 3;          // 0..127
            int kf  = (idx & 7) * 4;     // 0..28
            int grow = bm + r;
            float4 av = (grow < M)
                ? *reinterpret_cast<const float4*>(A + (size_t)grow * 256 + k0 + kf)
                : make_float4(0.f, 0.f, 0.f, 0.f);
            ushort4 hv, lv;
            hv.x = f2bf(av.x); lv.x = f2bf(av.x - bf2f(hv.x));
            hv.y = f2bf(av.y); lv.y = f2bf(av.y - bf2f(hv.y));
            hv.z = f2bf(av.z); lv.z = f2bf(av.z - bf2f(hv.z));
            hv.w = f2bf(av.w); lv.w = f2bf(av.w - bf2f(hv.w));
            *reinterpret_cast<ushort4*>(&Ah[r][kf]) = hv;
            *reinterpret_cast<ushort4*>(&Al[r][kf]) = lv;
        }
        // stage B: 128 n x 32 k from pre-split W2T (16B chunks)
        #pragma unroll
        for (int p = 0; p < 2; ++p) {
            int idx = p * 256 + tid;     // 0..511
            int n   = idx >> 2;          // 0..127
            int kc  = (idx & 3) * 8;     // 0,8,16,24
            const size_t go = (size_t)(bn + n) * 256 + k0 + kc;
            *reinterpret_cast<uint4*>(&Bh[n][kc]) = *reinterpret_cast<const uint4*>(WTh + go);
            *reinterpret_cast<uint4*>(&Bl[n][kc]) = *reinterpret_cast<const uint4*>(WTl + go);
        }
        __syncthreads();

        // B frags for this wave: n = wn*64 + nt*16 + c, k = q*8 .. q*8+7
        short8 bh[4], bl[4];
        #pragma unroll
        for (int nt = 0; nt < 4; ++nt) {
            bh[nt] = *reinterpret_cast<const short8*>(&Bh[wn * 64 + nt * 16 + c][q * 8]);
            bl[nt] = *reinterpret_cast<const short8*>(&Bl[wn * 64 + nt * 16 + c][q * 8]);
        }
        #pragma unroll
        for (int mt = 0; mt < 4; ++mt) {
            short8 ah = *reinterpret_cast<const short8*>(&Ah[wm * 64 + mt * 16 + c][q * 8]);
            short8 al = *reinterpret_cast<const short8*>(&Al[wm * 64 + mt * 16 + c][q * 8]);
            #pragma unroll
            for (int nt = 0; nt < 4; ++nt) {
                acc[mt][nt] = __builtin_amdgcn_mfma_f32_16x16x32_bf16(ah, bh[nt], acc[mt][nt], 0, 0, 0);
                acc[mt][nt] = __builtin_amdgcn_mfma_f32_16x16x32_bf16(ah, bl[nt], acc[mt][nt], 0, 0, 0);
                acc[mt][nt] = __builtin_amdgcn_mfma_f32_16x16x32_bf16(al, bh[nt], acc[mt][nt], 0, 0, 0);
            }
        }
        __syncthreads();
    }

    // ---- epilogue: bf16 C store ----
    #pragma unroll
    for (int mt = 0; mt < 4; ++mt) {
        #pragma unroll
        for (int r = 0; r < 4; ++r) {
            int gr = bm + wm * 64 + mt * 16 + q * 4 + r;
            if (gr < M) {
                #pragma unroll
                for (int nt = 0; nt < 4; ++nt) {
                    Cb[(size_t)gr * 256 + bn + wn * 64 + nt * 16 + c] = f2bf(acc[mt][nt][r]);
                }
            }
        }
    }
    // ---- fused es/ed (head = 64-col slab of this wave) ----
    int head = blockIdx.y * 2 + wn;
    float asv[4], adv[4];
    #pragma unroll
    for (int nt = 0; nt < 4; ++nt) {
        asv[nt] = as_[head * 64 + nt * 16 + c];
        adv[nt] = ad_[head * 64 + nt * 16 + c];
    }
    #pragma unroll
    for (int mt = 0; mt < 4; ++mt) {
        #pragma unroll
        for (int r = 0; r < 4; ++r) {
            float s = 0.f, d = 0.f;
            #pragma unroll
            for (int nt = 0; nt < 4; ++nt) {
                s += acc[mt][nt][r] * asv[nt];
                d += acc[mt][nt][r] * adv[nt];
            }
            #pragma unroll
            for (int off = 1; off < 16; off <<= 1) {
                s += __shfl_xor(s, off, 64);
                d += __shfl_xor(d, off, 64);
            }
            int gr = bm + wm * 64 + mt * 16 + q * 4 + r;
            if (c == 0 && gr < M) {
                es[(size_t)gr * 4 + head] = s;
                ed[(size_t)gr * 4 + head] = d;
            }
        }
    }
}

// ---------------- fp32 tiled GEMM with fused attention-coefficient epilogue ----------------
// (layers 1 and 3)
template <int H, int BF16C>
__global__ __launch_bounds__(256) void gemm_attn_kernel(const float* __restrict__ A,
                                                        const float* __restrict__ B,
                                                        float* __restrict__ Cf,
                                                        unsigned short* __restrict__ Cb,
                                                        const float* __restrict__ as_,
                                                        const float* __restrict__ ad_,
                                                        float* __restrict__ es,
                                                        float* __restrict__ ed,
                                                        int M, int K, int Ncol) {
    __shared__ __align__(16) float As[16][64];  // [k][m]
    __shared__ __align__(16) float Bs[16][64];  // [k][n]
    int tid = threadIdx.x;
    int bm = blockIdx.x * 64;
    int bn = blockIdx.y * 64;
    int tm = (tid >> 4) * 4;
    int tn = (tid & 15) * 4;
    float acc[4][4] = {};
    int ar  = tid >> 2;        // 0..63 row of A tile
    int akk = (tid & 3) * 4;   // 0,4,8,12
    int brr = tid >> 4;        // 0..15 row of B tile
    int bcc = (tid & 15) * 4;
    for (int k0 = 0; k0 < K; k0 += 16) {
        int grow = bm + ar;
        float4 av;
        if (grow < M) av = *reinterpret_cast<const float4*>(A + (size_t)grow * K + k0 + akk);
        else          av = make_float4(0.f, 0.f, 0.f, 0.f);
        As[akk + 0][ar] = av.x;
        As[akk + 1][ar] = av.y;
        As[akk + 2][ar] = av.z;
        As[akk + 3][ar] = av.w;
        float4 bv = *reinterpret_cast<const float4*>(B + (size_t)(k0 + brr) * Ncol + bn + bcc);
        *reinterpret_cast<float4*>(&Bs[brr][bcc]) = bv;
        __syncthreads();
        #pragma unroll
        for (int kk = 0; kk < 16; ++kk) {
            float4 a4 = *reinterpret_cast<const float4*>(&As[kk][tm]);
            float4 b4 = *reinterpret_cast<const float4*>(&Bs[kk][tn]);
            float a[4] = {a4.x, a4.y, a4.z, a4.w};
            float b[4] = {b4.x, b4.y, b4.z, b4.w};
            #pragma unroll
            for (int i = 0; i < 4; ++i)
                #pragma unroll
                for (int j = 0; j < 4; ++j) acc[i][j] += a[i] * b[j];
        }
        __syncthreads();
    }
    #pragma unroll
    for (int i = 0; i < 4; ++i) {
        int gr = bm + tm + i;
        if (gr < M) {
            if constexpr (BF16C) {
                ushort4 r;
                r.x = f2bf(acc[i][0]); r.y = f2bf(acc[i][1]);
                r.z = f2bf(acc[i][2]); r.w = f2bf(acc[i][3]);
                *reinterpret_cast<ushort4*>(Cb + (size_t)gr * Ncol + bn + tn) = r;
            } else {
                float4 r = make_float4(acc[i][0], acc[i][1], acc[i][2], acc[i][3]);
                *reinterpret_cast<float4*>(Cf + (size_t)gr * Ncol + bn + tn) = r;
            }
        }
    }
    // ---- fused es/ed epilogue ----
    int hy = blockIdx.y;  // head index (Ncol == H*64)
    float4 asv = *reinterpret_cast<const float4*>(as_ + (size_t)hy * 64 + tn);
    float4 adv = *reinterpret_cast<const float4*>(ad_ + (size_t)hy * 64 + tn);
    float sv[4], dv[4];
    #pragma unroll
    for (int i = 0; i < 4; ++i) {
        sv[i] = acc[i][0] * asv.x + acc[i][1] * asv.y + acc[i][2] * asv.z + acc[i][3] * asv.w;
        dv[i] = acc[i][0] * adv.x + acc[i][1] * adv.y + acc[i][2] * adv.z + acc[i][3] * adv.w;
    }
    #pragma unroll
    for (int off = 1; off < 16; off <<= 1) {
        #pragma unroll
        for (int i = 0; i < 4; ++i) {
            sv[i] += __shfl_xor(sv[i], off, 64);
            dv[i] += __shfl_xor(dv[i], off, 64);
        }
    }
    if ((tid & 15) == 0) {
        #pragma unroll
        for (int i = 0; i < 4; ++i) {
            int gr = bm + tm + i;
            if (gr < M) {
                es[(size_t)gr * H + hy] = sv[i];
                ed[(size_t)gr * H + hy] = dv[i];
            }
        }
    }
}

__device__ __forceinline__ float lrelu02(float x) { return x > 0.f ? x : 0.2f * x; }
__device__ __forceinline__ float eluf(float x)    { return x > 0.f ? x : expm1f(x); }

// ---------------- fused per-dst aggregation, H=4, bf16 gather operand ----------------
template <int ACT>
__global__ __launch_bounds__(256) void agg4_kernel(const unsigned short* __restrict__ hb,
                                                   const float* __restrict__ es,
                                                   const float* __restrict__ ed,
                                                   const int* __restrict__ rowptr,
                                                   const int* __restrict__ col,
                                                   const float* __restrict__ bias,
                                                   float* __restrict__ out, int N) {
    __shared__ int   slds[4][64];
    __shared__ float plds[4][4][68];   // +4 pad: heads land in different banks
    int sub  = threadIdx.x >> 6;
    int lane = threadIdx.x & 63;
    int node = blockIdx.x * 4 + sub;
    if (node >= N) return;
    int s = rowptr[node], t = rowptr[node + 1];

    float edv[4];
    #pragma unroll
    for (int h = 0; h < 4; ++h) edv[h] = ed[(size_t)node * 4 + h];

    // phase A: per-head max over incoming edges
    float mx[4] = {-3.0e38f, -3.0e38f, -3.0e38f, -3.0e38f};
    for (int base = s; base < t; base += 64) {
        int j = base + lane;
        if (j < t) {
            int sc = col[j];
            float4 e4 = *reinterpret_cast<const float4*>(es + (size_t)sc * 4);
            mx[0] = fmaxf(mx[0], lrelu02(e4.x + edv[0]));
            mx[1] = fmaxf(mx[1], lrelu02(e4.y + edv[1]));
            mx[2] = fmaxf(mx[2], lrelu02(e4.z + edv[2]));
            mx[3] = fmaxf(mx[3], lrelu02(e4.w + edv[3]));
        }
    }
    #pragma unroll
    for (int off = 32; off; off >>= 1)
        #pragma unroll
        for (int h = 0; h < 4; ++h) mx[h] = fmaxf(mx[h], __shfl_xor(mx[h], off, 64));

    // phase B: weights -> LDS, unnormalized gather-accumulate
    float den[4] = {0.f, 0.f, 0.f, 0.f};
    int hh = lane >> 4;  // this lane's head (4 dims per lane)
    float4 acc = make_float4(0.f, 0.f, 0.f, 0.f);
    for (int base = s; base < t; base += 64) {
        int j = base + lane;
        int m = t - base; if (m > 64) m = 64;
        int sc = 0;
        float p[4] = {0.f, 0.f, 0.f, 0.f};
        if (j < t) {
            sc = col[j];
            float4 e4 = *reinterpret_cast<const float4*>(es + (size_t)sc * 4);
            p[0] = __expf(lrelu02(e4.x + edv[0]) - mx[0]);
            p[1] = __expf(lrelu02(e4.y + edv[1]) - mx[1]);
            p[2] = __expf(lrelu02(e4.z + edv[2]) - mx[2]);
            p[3] = __expf(lrelu02(e4.w + edv[3]) - mx[3]);
        }
        slds[sub][lane] = sc;
        #pragma unroll
        for (int h = 0; h < 4; ++h) {
            den[h] += p[h];
            plds[sub][h][lane] = p[h];
        }
        #pragma unroll 4
        for (int jj = 0; jj < m; ++jj) {
            int scj = slds[sub][jj];
            float a = plds[sub][hh][jj];
            uint2 u = *reinterpret_cast<const uint2*>(hb + (size_t)scj * 256 + lane * 4);
            acc.x += __uint_as_float(u.x << 16)          * a;
            acc.y += __uint_as_float(u.x & 0xffff0000u)  * a;
            acc.z += __uint_as_float(u.y << 16)          * a;
            acc.w += __uint_as_float(u.y & 0xffff0000u)  * a;
        }
    }
    #pragma unroll
    for (int off = 32; off; off >>= 1)
        #pragma unroll
        for (int h = 0; h < 4; ++h) den[h] += __shfl_xor(den[h], off, 64);
    float inv = 1.f / den[hh];
    float4 bv = *reinterpret_cast<const float4*>(bias + lane * 4);
    float4 r;
    r.x = acc.x * inv + bv.x;
    r.y = acc.y * inv + bv.y;
    r.z = acc.z * inv + bv.z;
    r.w = acc.w * inv + bv.w;
    if (ACT) { r.x = eluf(r.x); r.y = eluf(r.y); r.z = eluf(r.z); r.w = eluf(r.w); }
    *reinterpret_cast<float4*>(out + (size_t)node * 256 + lane * 4) = r;
}

// ---------------- fused per-dst aggregation, H=1, fp32 gather (final layer) ----------------
__global__ __launch_bounds__(256) void agg1_kernel(const float* __restrict__ hbuf,
                                                   const float* __restrict__ es,
                                                   const float* __restrict__ ed,
                                                   const int* __restrict__ rowptr,
                                                   const int* __restrict__ col,
                                                   const float* __restrict__ bias,
                                                   float* __restrict__ out, int N) {
    __shared__ int   slds[4][64];
    __shared__ float plds[4][64];
    int sub  = threadIdx.x >> 6;
    int lane = threadIdx.x & 63;
    int node = blockIdx.x * 4 + sub;
    if (node >= N) return;
    int s = rowptr[node], t = rowptr[node + 1];
    float edv = ed[node];

    float mx = -3.0e38f;
    for (int base = s; base < t; base += 64) {
        int j = base + lane;
        if (j < t) mx = fmaxf(mx, lrelu02(es[col[j]] + edv));
    }
    #pragma unroll
    for (int off = 32; off; off >>= 1) mx = fmaxf(mx, __shfl_xor(mx, off, 64));

    float den = 0.f, acc = 0.f;
    for (int base = s; base < t; base += 64) {
        int j = base + lane;
        int m = t - base; if (m > 64) m = 64;
        int sc = 0;
        float p0 = 0.f;
        if (j < t) {
            sc = col[j];
            p0 = __expf(lrelu02(es[sc] + edv) - mx);
        }
        slds[sub][lane] = sc;
        plds[sub][lane] = p0;
        den += p0;
        #pragma unroll 4
        for (int jj = 0; jj < m; ++jj) {
            int scj = slds[sub][jj];
            float a = plds[sub][jj];
            acc += hbuf[(size_t)scj * 64 + lane] * a;
        }
    }
    #pragma unroll
    for (int off = 32; off; off >>= 1) den += __shfl_xor(den, off, 64);
    out[(size_t)node * 64 + lane] = acc * (1.f / den) + bias[lane];
}

// ---------------- graph mean ----------------
__global__ __launch_bounds__(256) void gmean_partial(const float* __restrict__ ne,
                                                     float* __restrict__ part, int N) {
    int d = threadIdx.x & 63, sub = threadIdx.x >> 6;
    int start = blockIdx.x * 4 + sub;
    float s = 0.f;
    for (int n = start; n < N; n += gridDim.x * 4) s += ne[(size_t)n * 64 + d];
    __shared__ float ls[256];
    ls[threadIdx.x] = s;
    __syncthreads();
    if (threadIdx.x < 64) {
        float v = ls[threadIdx.x] + ls[threadIdx.x + 64] + ls[threadIdx.x + 128] + ls[threadIdx.x + 192];
        part[blockIdx.x * 64 + d] = v;
    }
}

__global__ __launch_bounds__(64) void gmean_final(const float* __restrict__ part,
                                                  float* __restrict__ gout, int nblk, float invN) {
    int d = threadIdx.x;
    float s = 0.f;
    for (int b = 0; b < nblk; ++b) s += part[b * 64 + d];
    gout[d] = s * invN;
}

extern "C" void kernel_launch(void* const* d_in, const int* in_sizes, int n_in,
                              void* d_out, int out_size, void* d_ws, size_t ws_size,
                              hipStream_t stream) {
    const float* x   = (const float*)d_in[0];
    const int*   ei  = (const int*)d_in[1];
    const float* W1  = (const float*)d_in[2];
    const float* a1s = (const float*)d_in[3];
    const float* a1d = (const float*)d_in[4];
    const float* b1  = (const float*)d_in[5];
    const float* W2  = (const float*)d_in[6];
    const float* a2s = (const float*)d_in[7];
    const float* a2d = (const float*)d_in[8];
    const float* b2  = (const float*)d_in[9];
    const float* W3  = (const float*)d_in[10];
    const float* a3s = (const float*)d_in[11];
    const float* a3d = (const float*)d_in[12];
    const float* b3  = (const float*)d_in[13];
    float* out = (float*)d_out;

    const int N = NNODES;
    const int E = in_sizes[1] / 2;  // 800000
    const int NB = (N + 255) / 256; // scan blocks (196)

    // workspace carve (16B alignment maintained)
    char* w = (char*)d_ws;
    unsigned short* Hb = (unsigned short*)w; w += (size_t)N * 256 * 2;  // bf16 h (layers 1-2)
    float* B0 = (float*)w; w += (size_t)N * 256 * 4;   // fp32 buffer (gemm3 C / agg out)
    float* B1 = (float*)w; w += (size_t)N * 256 * 4;   // agg out ping-pong
    float* es = (float*)w; w += (size_t)N * 4 * 4;
    float* ed = (float*)w; w += (size_t)N * 4 * 4;
    unsigned short* W2Th = (unsigned short*)w; w += 256 * 256 * 2;
    unsigned short* W2Tl = (unsigned short*)w; w += 256 * 256 * 2;
    int* deg    = (int*)w; w += (size_t)N * 4;
    int* rowptr = (int*)w; w += (size_t)(N + 2) * 4;
    int* fill   = (int*)w; w += (size_t)N * 4;
    int* col    = (int*)w; w += (size_t)(E + N) * 4;
    int* bsum   = (int*)w; w += 256 * 4;
    int* boff   = (int*)w; w += 256 * 4;
    float* part = (float*)w; w += 128 * 64 * 4;
    (void)ws_size; (void)n_in; (void)out_size;

    // ---- CSR build (dst-sorted adjacency incl. self-loops) ----
    deg_init_kernel<<<NB, 256, 0, stream>>>(deg, N);
    deg_count_kernel<<<(E + 255) / 256, 256, 0, stream>>>(ei, deg, E);
    scan_partial_kernel<<<NB, 256, 0, stream>>>(deg, bsum, N);
    scan_blocks_kernel<<<1, 256, 0, stream>>>(bsum, boff, rowptr + N, NB);
    scan_final_kernel<<<NB, 256, 0, stream>>>(deg, boff, rowptr, fill, N);
    scatter_kernel<<<(E + N + 255) / 256, 256, 0, stream>>>(ei, fill, col, E, N);
    // W2 prep for MFMA (independent of CSR; cheap)
    w2t_prep_kernel<<<256, 256, 0, stream>>>(W2, W2Th, W2Tl);

    // ---- Layer 1: x[N,16] @ W1[16,256], H=4, C->bf16 ----
    gemm_attn_kernel<4, 1><<<dim3((N + 63) / 64, 4), 256, 0, stream>>>(
        x, W1, nullptr, Hb, a1s, a1d, es, ed, N, 16, 256);
    agg4_kernel<1><<<(N + 3) / 4, 256, 0, stream>>>(Hb, es, ed, rowptr, col, b1, B1, N);

    // ---- Layer 2: B1[N,256] @ W2[256,256], H=4, split-bf16 MFMA ----
    gemm2_mfma_kernel<<<dim3((N + 127) / 128, 2), 256, 0, stream>>>(
        B1, W2Th, W2Tl, Hb, a2s, a2d, es, ed, N);
    agg4_kernel<1><<<(N + 3) / 4, 256, 0, stream>>>(Hb, es, ed, rowptr, col, b2, B0, N);

    // ---- Layer 3: B0[N,256] @ W3[256,64], H=1, fp32 C (feeds output directly) ----
    gemm_attn_kernel<1, 0><<<dim3((N + 63) / 64, 1), 256, 0, stream>>>(
        B0, W3, B1, nullptr, a3s, a3d, es, ed, N, 256, 64);
    agg1_kernel<<<(N + 3) / 4, 256, 0, stream>>>(B1, es, ed, rowptr, col, b3, out, N);

    // ---- graph mean over nodes ----
    gmean_partial<<<128, 256, 0, stream>>>(out, part, N);
    gmean_final<<<1, 64, 0, stream>>>(part, out + (size_t)N * 64, 128, 1.0f / N);
}

// Round 6
// 480.608 us; speedup vs baseline: 1.8730x; 1.0887x over previous
//
#include <hip/hip_runtime.h>
#include <math.h>

#define NNODES 50000

typedef __attribute__((ext_vector_type(8))) short short8;   // 8 bf16 (4 VGPRs)
typedef __attribute__((ext_vector_type(4))) float f32x4;    // MFMA accumulator

__device__ __forceinline__ unsigned short f2bf(float f) {
    unsigned u = __float_as_uint(f);
    u += 0x7fffu + ((u >> 16) & 1);   // RTN-even
    return (unsigned short)(u >> 16);
}
__device__ __forceinline__ float bf2f(unsigned short h) {
    return __uint_as_float(((unsigned)h) << 16);
}

// ---------------- CSR build ----------------
__global__ __launch_bounds__(256) void deg_init_kernel(int* __restrict__ deg, int N) {
    int i = blockIdx.x * 256 + threadIdx.x;
    if (i < N) deg[i] = 1;  // self-loop
}

__global__ __launch_bounds__(256) void deg_count_kernel(const int* __restrict__ ei,
                                                        int* __restrict__ deg, int E) {
    int i = blockIdx.x * 256 + threadIdx.x;
    if (i < E) atomicAdd(&deg[ei[E + i]], 1);
}

__global__ __launch_bounds__(256) void scan_partial_kernel(const int* __restrict__ deg,
                                                           int* __restrict__ bsum, int N) {
    __shared__ int ls[256];
    int t = threadIdx.x;
    int i = blockIdx.x * 256 + t;
    ls[t] = (i < N) ? deg[i] : 0;
    __syncthreads();
    #pragma unroll
    for (int off = 128; off; off >>= 1) {
        if (t < off) ls[t] += ls[t + off];
        __syncthreads();
    }
    if (t == 0) bsum[blockIdx.x] = ls[0];
}

__global__ __launch_bounds__(256) void scan_blocks_kernel(const int* __restrict__ bsum,
                                                          int* __restrict__ boff,
                                                          int* __restrict__ rowptrN, int nblk) {
    __shared__ int ls[256];
    int t = threadIdx.x;
    int v = (t < nblk) ? bsum[t] : 0;
    ls[t] = v;
    __syncthreads();
    for (int off = 1; off < 256; off <<= 1) {
        int u = (t >= off) ? ls[t - off] : 0;
        __syncthreads();
        ls[t] += u;
        __syncthreads();
    }
    if (t < nblk) boff[t] = ls[t] - v;
    if (t == 255) *rowptrN = ls[255];
}

__global__ __launch_bounds__(256) void scan_final_kernel(const int* __restrict__ deg,
                                                         const int* __restrict__ boff,
                                                         int* __restrict__ rowptr,
                                                         int* __restrict__ fill, int N) {
    __shared__ int ls[256];
    int t = threadIdx.x;
    int i = blockIdx.x * 256 + t;
    int v = (i < N) ? deg[i] : 0;
    ls[t] = v;
    __syncthreads();
    for (int off = 1; off < 256; off <<= 1) {
        int u = (t >= off) ? ls[t - off] : 0;
        __syncthreads();
        ls[t] += u;
        __syncthreads();
    }
    if (i < N) {
        int e = boff[blockIdx.x] + ls[t] - v;
        rowptr[i] = e;
        fill[i] = e;
    }
}

__global__ __launch_bounds__(256) void scatter_kernel(const int* __restrict__ ei,
                                                      int* __restrict__ fill,
                                                      int* __restrict__ col, int E, int N) {
    int i = blockIdx.x * 256 + threadIdx.x;
    int total = E + N;
    if (i >= total) return;
    int s, d;
    if (i < E) { s = ei[i]; d = ei[E + i]; }
    else       { s = i - E; d = s; }
    int pos = atomicAdd(&fill[d], 1);
    col[pos] = s;
}

// ---------------- weight prep: transpose + split fp32 -> bf16 hi/lo, [n][k] layout ----------------
__global__ __launch_bounds__(256) void w2t_prep_kernel(const float* __restrict__ W,
                                                       unsigned short* __restrict__ Th,
                                                       unsigned short* __restrict__ Tl) {
    int k = blockIdx.x, n = threadIdx.x;   // 256 x 256
    float w = W[k * 256 + n];
    unsigned short h = f2bf(w);
    unsigned short l = f2bf(w - bf2f(h));
    Th[n * 256 + k] = h;
    Tl[n * 256 + k] = l;
}

__global__ __launch_bounds__(256) void w3t_prep_kernel(const float* __restrict__ W,
                                                       unsigned short* __restrict__ Th,
                                                       unsigned short* __restrict__ Tl) {
    int n = blockIdx.x, k = threadIdx.x;   // 64 x 256
    float w = W[k * 64 + n];
    unsigned short h = f2bf(w);
    unsigned short l = f2bf(w - bf2f(h));
    Th[n * 256 + k] = h;
    Tl[n * 256 + k] = l;
}

#define LDK 40

// ---------------- layer-2 GEMM: split-bf16 MFMA, fused es/ed epilogue ----------------
__global__ __launch_bounds__(256) void gemm2_mfma_kernel(const float* __restrict__ A,
                                                         const unsigned short* __restrict__ WTh,
                                                         const unsigned short* __restrict__ WTl,
                                                         unsigned short* __restrict__ Cb,
                                                         const float* __restrict__ as_,
                                                         const float* __restrict__ ad_,
                                                         float* __restrict__ es,
                                                         float* __restrict__ ed,
                                                         int M) {
    __shared__ __align__(16) unsigned short Ah[128][LDK], Al[128][LDK];
    __shared__ __align__(16) unsigned short Bh[128][LDK], Bl[128][LDK];
    int tid  = threadIdx.x;
    int lane = tid & 63, wave = tid >> 6;
    int wm = wave >> 1, wn = wave & 1;
    int bm = blockIdx.x * 128;
    int bn = blockIdx.y * 128;
    int c = lane & 15, q = lane >> 4;

    f32x4 acc[4][4] = {};  // [mt][nt], C/D: row = q*4+r, col = c

    for (int k0 = 0; k0 < 256; k0 += 32) {
        #pragma unroll
        for (int p = 0; p < 4; ++p) {
            int idx = p * 256 + tid;
            int r   = idx >> 3;
            int kf  = (idx & 7) * 4;
            int grow = bm + r;
            float4 av = (grow < M)
                ? *reinterpret_cast<const float4*>(A + (size_t)grow * 256 + k0 + kf)
                : make_float4(0.f, 0.f, 0.f, 0.f);
            ushort4 hv, lv;
            hv.x = f2bf(av.x); lv.x = f2bf(av.x - bf2f(hv.x));
            hv.y = f2bf(av.y); lv.y = f2bf(av.y - bf2f(hv.y));
            hv.z = f2bf(av.z); lv.z = f2bf(av.z - bf2f(hv.z));
            hv.w = f2bf(av.w); lv.w = f2bf(av.w - bf2f(hv.w));
            *reinterpret_cast<ushort4*>(&Ah[r][kf]) = hv;
            *reinterpret_cast<ushort4*>(&Al[r][kf]) = lv;
        }
        #pragma unroll
        for (int p = 0; p < 2; ++p) {
            int idx = p * 256 + tid;
            int n   = idx >> 2;
            int kc  = (idx & 3) * 8;
            const size_t go = (size_t)(bn + n) * 256 + k0 + kc;
            *reinterpret_cast<uint4*>(&Bh[n][kc]) = *reinterpret_cast<const uint4*>(WTh + go);
            *reinterpret_cast<uint4*>(&Bl[n][kc]) = *reinterpret_cast<const uint4*>(WTl + go);
        }
        __syncthreads();

        short8 bh[4], bl[4];
        #pragma unroll
        for (int nt = 0; nt < 4; ++nt) {
            bh[nt] = *reinterpret_cast<const short8*>(&Bh[wn * 64 + nt * 16 + c][q * 8]);
            bl[nt] = *reinterpret_cast<const short8*>(&Bl[wn * 64 + nt * 16 + c][q * 8]);
        }
        #pragma unroll
        for (int mt = 0; mt < 4; ++mt) {
            short8 ah = *reinterpret_cast<const short8*>(&Ah[wm * 64 + mt * 16 + c][q * 8]);
            short8 al = *reinterpret_cast<const short8*>(&Al[wm * 64 + mt * 16 + c][q * 8]);
            #pragma unroll
            for (int nt = 0; nt < 4; ++nt) {
                acc[mt][nt] = __builtin_amdgcn_mfma_f32_16x16x32_bf16(ah, bh[nt], acc[mt][nt], 0, 0, 0);
                acc[mt][nt] = __builtin_amdgcn_mfma_f32_16x16x32_bf16(ah, bl[nt], acc[mt][nt], 0, 0, 0);
                acc[mt][nt] = __builtin_amdgcn_mfma_f32_16x16x32_bf16(al, bh[nt], acc[mt][nt], 0, 0, 0);
            }
        }
        __syncthreads();
    }

    #pragma unroll
    for (int mt = 0; mt < 4; ++mt) {
        #pragma unroll
        for (int r = 0; r < 4; ++r) {
            int gr = bm + wm * 64 + mt * 16 + q * 4 + r;
            if (gr < M) {
                #pragma unroll
                for (int nt = 0; nt < 4; ++nt) {
                    Cb[(size_t)gr * 256 + bn + wn * 64 + nt * 16 + c] = f2bf(acc[mt][nt][r]);
                }
            }
        }
    }
    int head = blockIdx.y * 2 + wn;
    float asv[4], adv[4];
    #pragma unroll
    for (int nt = 0; nt < 4; ++nt) {
        asv[nt] = as_[head * 64 + nt * 16 + c];
        adv[nt] = ad_[head * 64 + nt * 16 + c];
    }
    #pragma unroll
    for (int mt = 0; mt < 4; ++mt) {
        #pragma unroll
        for (int r = 0; r < 4; ++r) {
            float s = 0.f, d = 0.f;
            #pragma unroll
            for (int nt = 0; nt < 4; ++nt) {
                s += acc[mt][nt][r] * asv[nt];
                d += acc[mt][nt][r] * adv[nt];
            }
            #pragma unroll
            for (int off = 1; off < 16; off <<= 1) {
                s += __shfl_xor(s, off, 64);
                d += __shfl_xor(d, off, 64);
            }
            int gr = bm + wm * 64 + mt * 16 + q * 4 + r;
            if (c == 0 && gr < M) {
                es[(size_t)gr * 4 + head] = s;
                ed[(size_t)gr * 4 + head] = d;
            }
        }
    }
}

// ---------------- layer-3 GEMM: bf16-A MFMA (A already bf16), W3 split hi/lo ----------------
// C[M,64] = Ab[M,256] @ W3[256,64]; tile 128 rows x 64 cols, 4 waves each 32x64.
__global__ __launch_bounds__(256) void gemm3_mfma_kernel(const unsigned short* __restrict__ Ab,
                                                         const unsigned short* __restrict__ WTh,
                                                         const unsigned short* __restrict__ WTl,
                                                         unsigned short* __restrict__ Cb,
                                                         const float* __restrict__ as_,
                                                         const float* __restrict__ ad_,
                                                         float* __restrict__ es,
                                                         float* __restrict__ ed,
                                                         int M) {
    __shared__ __align__(16) unsigned short Ah[128][LDK];
    __shared__ __align__(16) unsigned short Bh[64][LDK], Bl[64][LDK];
    int tid = threadIdx.x, lane = tid & 63, wave = tid >> 6;
    int bm = blockIdx.x * 128;
    int c = lane & 15, q = lane >> 4;
    f32x4 acc[2][4] = {};   // [mt][nt]

    for (int k0 = 0; k0 < 256; k0 += 32) {
        #pragma unroll
        for (int p = 0; p < 2; ++p) {
            int idx = p * 256 + tid;     // 0..511
            int r   = idx >> 2;          // 0..127
            int kf  = (idx & 3) * 8;
            int grow = bm + r;
            uint4 v = (grow < M)
                ? *reinterpret_cast<const uint4*>(Ab + (size_t)grow * 256 + k0 + kf)
                : make_uint4(0u, 0u, 0u, 0u);
            *reinterpret_cast<uint4*>(&Ah[r][kf]) = v;
        }
        {
            int n  = tid >> 2;           // 0..63
            int kc = (tid & 3) * 8;
            size_t go = (size_t)n * 256 + k0 + kc;
            *reinterpret_cast<uint4*>(&Bh[n][kc]) = *reinterpret_cast<const uint4*>(WTh + go);
            *reinterpret_cast<uint4*>(&Bl[n][kc]) = *reinterpret_cast<const uint4*>(WTl + go);
        }
        __syncthreads();

        short8 bh[4], bl[4];
        #pragma unroll
        for (int nt = 0; nt < 4; ++nt) {
            bh[nt] = *reinterpret_cast<const short8*>(&Bh[nt * 16 + c][q * 8]);
            bl[nt] = *reinterpret_cast<const short8*>(&Bl[nt * 16 + c][q * 8]);
        }
        #pragma unroll
        for (int mt = 0; mt < 2; ++mt) {
            short8 a = *reinterpret_cast<const short8*>(&Ah[wave * 32 + mt * 16 + c][q * 8]);
            #pragma unroll
            for (int nt = 0; nt < 4; ++nt) {
                acc[mt][nt] = __builtin_amdgcn_mfma_f32_16x16x32_bf16(a, bh[nt], acc[mt][nt], 0, 0, 0);
                acc[mt][nt] = __builtin_amdgcn_mfma_f32_16x16x32_bf16(a, bl[nt], acc[mt][nt], 0, 0, 0);
            }
        }
        __syncthreads();
    }

    float asv[4], adv[4];
    #pragma unroll
    for (int nt = 0; nt < 4; ++nt) { asv[nt] = as_[nt * 16 + c]; adv[nt] = ad_[nt * 16 + c]; }
    #pragma unroll
    for (int mt = 0; mt < 2; ++mt) {
        #pragma unroll
        for (int r = 0; r < 4; ++r) {
            int gr = bm + wave * 32 + mt * 16 + q * 4 + r;
            bool ok = gr < M;
            if (ok) {
                #pragma unroll
                for (int nt = 0; nt < 4; ++nt)
                    Cb[(size_t)gr * 64 + nt * 16 + c] = f2bf(acc[mt][nt][r]);
            }
            float s = 0.f, d = 0.f;
            #pragma unroll
            for (int nt = 0; nt < 4; ++nt) {
                s += acc[mt][nt][r] * asv[nt];
                d += acc[mt][nt][r] * adv[nt];
            }
            #pragma unroll
            for (int off = 1; off < 16; off <<= 1) {
                s += __shfl_xor(s, off, 64);
                d += __shfl_xor(d, off, 64);
            }
            if (c == 0 && ok) { es[gr] = s; ed[gr] = d; }
        }
    }
}

// ---------------- layer-1 fp32 GEMM (K=16) with fused es/ed epilogue ----------------
template <int H>
__global__ __launch_bounds__(256) void gemm_attn_kernel(const float* __restrict__ A,
                                                        const float* __restrict__ B,
                                                        unsigned short* __restrict__ Cb,
                                                        const float* __restrict__ as_,
                                                        const float* __restrict__ ad_,
                                                        float* __restrict__ es,
                                                        float* __restrict__ ed,
                                                        int M, int K, int Ncol) {
    __shared__ __align__(16) float As[16][64];
    __shared__ __align__(16) float Bs[16][64];
    int tid = threadIdx.x;
    int bm = blockIdx.x * 64;
    int bn = blockIdx.y * 64;
    int tm = (tid >> 4) * 4;
    int tn = (tid & 15) * 4;
    float acc[4][4] = {};
    int ar  = tid >> 2;
    int akk = (tid & 3) * 4;
    int brr = tid >> 4;
    int bcc = (tid & 15) * 4;
    for (int k0 = 0; k0 < K; k0 += 16) {
        int grow = bm + ar;
        float4 av;
        if (grow < M) av = *reinterpret_cast<const float4*>(A + (size_t)grow * K + k0 + akk);
        else          av = make_float4(0.f, 0.f, 0.f, 0.f);
        As[akk + 0][ar] = av.x;
        As[akk + 1][ar] = av.y;
        As[akk + 2][ar] = av.z;
        As[akk + 3][ar] = av.w;
        float4 bv = *reinterpret_cast<const float4*>(B + (size_t)(k0 + brr) * Ncol + bn + bcc);
        *reinterpret_cast<float4*>(&Bs[brr][bcc]) = bv;
        __syncthreads();
        #pragma unroll
        for (int kk = 0; kk < 16; ++kk) {
            float4 a4 = *reinterpret_cast<const float4*>(&As[kk][tm]);
            float4 b4 = *reinterpret_cast<const float4*>(&Bs[kk][tn]);
            float a[4] = {a4.x, a4.y, a4.z, a4.w};
            float b[4] = {b4.x, b4.y, b4.z, b4.w};
            #pragma unroll
            for (int i = 0; i < 4; ++i)
                #pragma unroll
                for (int j = 0; j < 4; ++j) acc[i][j] += a[i] * b[j];
        }
        __syncthreads();
    }
    #pragma unroll
    for (int i = 0; i < 4; ++i) {
        int gr = bm + tm + i;
        if (gr < M) {
            ushort4 r;
            r.x = f2bf(acc[i][0]); r.y = f2bf(acc[i][1]);
            r.z = f2bf(acc[i][2]); r.w = f2bf(acc[i][3]);
            *reinterpret_cast<ushort4*>(Cb + (size_t)gr * Ncol + bn + tn) = r;
        }
    }
    int hy = blockIdx.y;
    float4 asv = *reinterpret_cast<const float4*>(as_ + (size_t)hy * 64 + tn);
    float4 adv = *reinterpret_cast<const float4*>(ad_ + (size_t)hy * 64 + tn);
    float sv[4], dv[4];
    #pragma unroll
    for (int i = 0; i < 4; ++i) {
        sv[i] = acc[i][0] * asv.x + acc[i][1] * asv.y + acc[i][2] * asv.z + acc[i][3] * asv.w;
        dv[i] = acc[i][0] * adv.x + acc[i][1] * adv.y + acc[i][2] * adv.z + acc[i][3] * adv.w;
    }
    #pragma unroll
    for (int off = 1; off < 16; off <<= 1) {
        #pragma unroll
        for (int i = 0; i < 4; ++i) {
            sv[i] += __shfl_xor(sv[i], off, 64);
            dv[i] += __shfl_xor(dv[i], off, 64);
        }
    }
    if ((tid & 15) == 0) {
        #pragma unroll
        for (int i = 0; i < 4; ++i) {
            int gr = bm + tm + i;
            if (gr < M) {
                es[(size_t)gr * H + hy] = sv[i];
                ed[(size_t)gr * H + hy] = dv[i];
            }
        }
    }
}

__device__ __forceinline__ float lrelu02(float x) { return x > 0.f ? x : 0.2f * x; }
__device__ __forceinline__ float eluf(float x)    { return x > 0.f ? x : expm1f(x); }

// ---------------- fused per-dst aggregation, H=4, bf16 gather, single-pass softmax ----------------
// No max subtraction: logits are lrelu-compressed (|e| << 88), exp cannot overflow fp32.
// OUTBF16: emit ELU output as bf16 (feeds gemm3 MFMA A operand) vs fp32.
template <int ACT, int OUTBF16>
__global__ __launch_bounds__(256) void agg4_kernel(const unsigned short* __restrict__ hb,
                                                   const float* __restrict__ es,
                                                   const float* __restrict__ ed,
                                                   const int* __restrict__ rowptr,
                                                   const int* __restrict__ col,
                                                   const float* __restrict__ bias,
                                                   void* __restrict__ outp, int N) {
    __shared__ int   slds[4][64];
    __shared__ float plds[4][4][68];   // +4 pad: heads land in different banks
    int sub  = threadIdx.x >> 6;
    int lane = threadIdx.x & 63;
    int node = blockIdx.x * 4 + sub;
    if (node >= N) return;
    int s = rowptr[node], t = rowptr[node + 1];

    float edv[4];
    #pragma unroll
    for (int h = 0; h < 4; ++h) edv[h] = ed[(size_t)node * 4 + h];

    float den[4] = {0.f, 0.f, 0.f, 0.f};
    int hh = lane >> 4;
    float4 acc = make_float4(0.f, 0.f, 0.f, 0.f);
    for (int base = s; base < t; base += 64) {
        int j = base + lane;
        int m = t - base; if (m > 64) m = 64;
        int sc = 0;
        float p[4] = {0.f, 0.f, 0.f, 0.f};
        if (j < t) {
            sc = col[j];
            float4 e4 = *reinterpret_cast<const float4*>(es + (size_t)sc * 4);
            p[0] = __expf(lrelu02(e4.x + edv[0]));
            p[1] = __expf(lrelu02(e4.y + edv[1]));
            p[2] = __expf(lrelu02(e4.z + edv[2]));
            p[3] = __expf(lrelu02(e4.w + edv[3]));
        }
        slds[sub][lane] = sc;
        #pragma unroll
        for (int h = 0; h < 4; ++h) {
            den[h] += p[h];
            plds[sub][h][lane] = p[h];
        }
        #pragma unroll 4
        for (int jj = 0; jj < m; ++jj) {
            int scj = slds[sub][jj];
            float a = plds[sub][hh][jj];
            uint2 u = *reinterpret_cast<const uint2*>(hb + (size_t)scj * 256 + lane * 4);
            acc.x += __uint_as_float(u.x << 16)          * a;
            acc.y += __uint_as_float(u.x & 0xffff0000u)  * a;
            acc.z += __uint_as_float(u.y << 16)          * a;
            acc.w += __uint_as_float(u.y & 0xffff0000u)  * a;
        }
    }
    #pragma unroll
    for (int off = 32; off; off >>= 1)
        #pragma unroll
        for (int h = 0; h < 4; ++h) den[h] += __shfl_xor(den[h], off, 64);
    float inv = 1.f / den[hh];
    float4 bv = *reinterpret_cast<const float4*>(bias + lane * 4);
    float4 r;
    r.x = acc.x * inv + bv.x;
    r.y = acc.y * inv + bv.y;
    r.z = acc.z * inv + bv.z;
    r.w = acc.w * inv + bv.w;
    if (ACT) { r.x = eluf(r.x); r.y = eluf(r.y); r.z = eluf(r.z); r.w = eluf(r.w); }
    if constexpr (OUTBF16) {
        ushort4 o;
        o.x = f2bf(r.x); o.y = f2bf(r.y); o.z = f2bf(r.z); o.w = f2bf(r.w);
        *reinterpret_cast<ushort4*>((unsigned short*)outp + (size_t)node * 256 + lane * 4) = o;
    } else {
        *reinterpret_cast<float4*>((float*)outp + (size_t)node * 256 + lane * 4) = r;
    }
}

// ---------------- fused per-dst aggregation, H=1, bf16 gather, single-pass ----------------
__global__ __launch_bounds__(256) void agg1_kernel(const unsigned short* __restrict__ hb,
                                                   const float* __restrict__ es,
                                                   const float* __restrict__ ed,
                                                   const int* __restrict__ rowptr,
                                                   const int* __restrict__ col,
                                                   const float* __restrict__ bias,
                                                   float* __restrict__ out, int N) {
    __shared__ int   slds[4][64];
    __shared__ float plds[4][64];
    int sub  = threadIdx.x >> 6;
    int lane = threadIdx.x & 63;
    int node = blockIdx.x * 4 + sub;
    if (node >= N) return;
    int s = rowptr[node], t = rowptr[node + 1];
    float edv = ed[node];

    float den = 0.f, acc = 0.f;
    for (int base = s; base < t; base += 64) {
        int j = base + lane;
        int m = t - base; if (m > 64) m = 64;
        int sc = 0;
        float p0 = 0.f;
        if (j < t) {
            sc = col[j];
            p0 = __expf(lrelu02(es[sc] + edv));
        }
        slds[sub][lane] = sc;
        plds[sub][lane] = p0;
        den += p0;
        #pragma unroll 4
        for (int jj = 0; jj < m; ++jj) {
            int scj = slds[sub][jj];
            float a = plds[sub][jj];
            acc += bf2f(hb[(size_t)scj * 64 + lane]) * a;
        }
    }
    #pragma unroll
    for (int off = 32; off; off >>= 1) den += __shfl_xor(den, off, 64);
    out[(size_t)node * 64 + lane] = acc * (1.f / den) + bias[lane];
}

// ---------------- graph mean ----------------
__global__ __launch_bounds__(256) void gmean_partial(const float* __restrict__ ne,
                                                     float* __restrict__ part, int N) {
    int d = threadIdx.x & 63, sub = threadIdx.x >> 6;
    int start = blockIdx.x * 4 + sub;
    float s = 0.f;
    for (int n = start; n < N; n += gridDim.x * 4) s += ne[(size_t)n * 64 + d];
    __shared__ float ls[256];
    ls[threadIdx.x] = s;
    __syncthreads();
    if (threadIdx.x < 64) {
        float v = ls[threadIdx.x] + ls[threadIdx.x + 64] + ls[threadIdx.x + 128] + ls[threadIdx.x + 192];
        part[blockIdx.x * 64 + d] = v;
    }
}

__global__ __launch_bounds__(64) void gmean_final(const float* __restrict__ part,
                                                  float* __restrict__ gout, int nblk, float invN) {
    int d = threadIdx.x;
    float s = 0.f;
    for (int b = 0; b < nblk; ++b) s += part[b * 64 + d];
    gout[d] = s * invN;
}

extern "C" void kernel_launch(void* const* d_in, const int* in_sizes, int n_in,
                              void* d_out, int out_size, void* d_ws, size_t ws_size,
                              hipStream_t stream) {
    const float* x   = (const float*)d_in[0];
    const int*   ei  = (const int*)d_in[1];
    const float* W1  = (const float*)d_in[2];
    const float* a1s = (const float*)d_in[3];
    const float* a1d = (const float*)d_in[4];
    const float* b1  = (const float*)d_in[5];
    const float* W2  = (const float*)d_in[6];
    const float* a2s = (const float*)d_in[7];
    const float* a2d = (const float*)d_in[8];
    const float* b2  = (const float*)d_in[9];
    const float* W3  = (const float*)d_in[10];
    const float* a3s = (const float*)d_in[11];
    const float* a3d = (const float*)d_in[12];
    const float* b3  = (const float*)d_in[13];
    float* out = (float*)d_out;

    const int N = NNODES;
    const int E = in_sizes[1] / 2;  // 800000
    const int NB = (N + 255) / 256;

    // workspace carve (16B alignment maintained)
    char* w = (char*)d_ws;
    unsigned short* Hb  = (unsigned short*)w; w += (size_t)N * 256 * 2;  // h1/h2 bf16 (agg4 gather)
    unsigned short* B0b = (unsigned short*)w; w += (size_t)N * 256 * 2;  // agg2 out bf16 (gemm3 A)
    unsigned short* H3b = (unsigned short*)w; w += (size_t)N * 64 * 2;   // h3 bf16 (agg1 gather)
    float* B1 = (float*)w; w += (size_t)N * 256 * 4;                     // agg1(layer1) out fp32 (gemm2 A)
    float* es = (float*)w; w += (size_t)N * 4 * 4;
    float* ed = (float*)w; w += (size_t)N * 4 * 4;
    unsigned short* W2Th = (unsigned short*)w; w += 256 * 256 * 2;
    unsigned short* W2Tl = (unsigned short*)w; w += 256 * 256 * 2;
    unsigned short* W3Th = (unsigned short*)w; w += 64 * 256 * 2;
    unsigned short* W3Tl = (unsigned short*)w; w += 64 * 256 * 2;
    int* deg    = (int*)w; w += (size_t)N * 4;
    int* rowptr = (int*)w; w += (size_t)(N + 2) * 4;
    int* fill   = (int*)w; w += (size_t)N * 4;
    int* col    = (int*)w; w += (size_t)(E + N) * 4;
    int* bsum   = (int*)w; w += 256 * 4;
    int* boff   = (int*)w; w += 256 * 4;
    float* part = (float*)w; w += 128 * 64 * 4;
    (void)ws_size; (void)n_in; (void)out_size;

    // ---- CSR build ----
    deg_init_kernel<<<NB, 256, 0, stream>>>(deg, N);
    deg_count_kernel<<<(E + 255) / 256, 256, 0, stream>>>(ei, deg, E);
    scan_partial_kernel<<<NB, 256, 0, stream>>>(deg, bsum, N);
    scan_blocks_kernel<<<1, 256, 0, stream>>>(bsum, boff, rowptr + N, NB);
    scan_final_kernel<<<NB, 256, 0, stream>>>(deg, boff, rowptr, fill, N);
    scatter_kernel<<<(E + N + 255) / 256, 256, 0, stream>>>(ei, fill, col, E, N);
    // weight prep
    w2t_prep_kernel<<<256, 256, 0, stream>>>(W2, W2Th, W2Tl);
    w3t_prep_kernel<<<64, 256, 0, stream>>>(W3, W3Th, W3Tl);

    // ---- Layer 1: x[N,16] @ W1[16,256], fp32 VALU, C->bf16 ----
    gemm_attn_kernel<4><<<dim3((N + 63) / 64, 4), 256, 0, stream>>>(
        x, W1, Hb, a1s, a1d, es, ed, N, 16, 256);
    agg4_kernel<1, 0><<<(N + 3) / 4, 256, 0, stream>>>(Hb, es, ed, rowptr, col, b1, B1, N);

    // ---- Layer 2: B1[N,256] @ W2, split-bf16 MFMA ----
    gemm2_mfma_kernel<<<dim3((N + 127) / 128, 2), 256, 0, stream>>>(
        B1, W2Th, W2Tl, Hb, a2s, a2d, es, ed, N);
    agg4_kernel<1, 1><<<(N + 3) / 4, 256, 0, stream>>>(Hb, es, ed, rowptr, col, b2, B0b, N);

    // ---- Layer 3: B0b[N,256] @ W3, bf16-A MFMA ----
    gemm3_mfma_kernel<<<(N + 127) / 128, 256, 0, stream>>>(
        B0b, W3Th, W3Tl, H3b, a3s, a3d, es, ed, N);
    agg1_kernel<<<(N + 3) / 4, 256, 0, stream>>>(H3b, es, ed, rowptr, col, b3, out, N);

    // ---- graph mean ----
    gmean_partial<<<128, 256, 0, stream>>>(out, part, N);
    gmean_final<<<1, 64, 0, stream>>>(part, out + (size_t)N * 64, 128, 1.0f / N);
}

// Round 7
// 467.390 us; speedup vs baseline: 1.9260x; 1.0283x over previous
//
#include <hip/hip_runtime.h>
#include <math.h>

#define NNODES 50000

typedef __attribute__((ext_vector_type(8))) short short8;   // 8 bf16 (4 VGPRs)
typedef __attribute__((ext_vector_type(4))) float f32x4;    // MFMA accumulator

__device__ __forceinline__ unsigned short f2bf(float f) {
    unsigned u = __float_as_uint(f);
    u += 0x7fffu + ((u >> 16) & 1);   // RTN-even
    return (unsigned short)(u >> 16);
}
__device__ __forceinline__ float bf2f(unsigned short h) {
    return __uint_as_float(((unsigned)h) << 16);
}
__device__ __forceinline__ float bflo(unsigned u) { return __uint_as_float(u << 16); }
__device__ __forceinline__ float bfhi(unsigned u) { return __uint_as_float(u & 0xffff0000u); }

// ---------------- CSR build ----------------
__global__ __launch_bounds__(256) void deg_init_kernel(int* __restrict__ deg, int N) {
    int i = blockIdx.x * 256 + threadIdx.x;
    if (i < N) deg[i] = 1;  // self-loop
}

__global__ __launch_bounds__(256) void deg_count_kernel(const int* __restrict__ ei,
                                                        int* __restrict__ deg, int E) {
    int i = blockIdx.x * 256 + threadIdx.x;
    if (i < E) atomicAdd(&deg[ei[E + i]], 1);
}

__global__ __launch_bounds__(256) void scan_partial_kernel(const int* __restrict__ deg,
                                                           int* __restrict__ bsum, int N) {
    __shared__ int ls[256];
    int t = threadIdx.x;
    int i = blockIdx.x * 256 + t;
    ls[t] = (i < N) ? deg[i] : 0;
    __syncthreads();
    #pragma unroll
    for (int off = 128; off; off >>= 1) {
        if (t < off) ls[t] += ls[t + off];
        __syncthreads();
    }
    if (t == 0) bsum[blockIdx.x] = ls[0];
}

__global__ __launch_bounds__(256) void scan_blocks_kernel(const int* __restrict__ bsum,
                                                          int* __restrict__ boff,
                                                          int* __restrict__ rowptrN, int nblk) {
    __shared__ int ls[256];
    int t = threadIdx.x;
    int v = (t < nblk) ? bsum[t] : 0;
    ls[t] = v;
    __syncthreads();
    for (int off = 1; off < 256; off <<= 1) {
        int u = (t >= off) ? ls[t - off] : 0;
        __syncthreads();
        ls[t] += u;
        __syncthreads();
    }
    if (t < nblk) boff[t] = ls[t] - v;
    if (t == 255) *rowptrN = ls[255];
}

__global__ __launch_bounds__(256) void scan_final_kernel(const int* __restrict__ deg,
                                                         const int* __restrict__ boff,
                                                         int* __restrict__ rowptr,
                                                         int* __restrict__ fill, int N) {
    __shared__ int ls[256];
    int t = threadIdx.x;
    int i = blockIdx.x * 256 + t;
    int v = (i < N) ? deg[i] : 0;
    ls[t] = v;
    __syncthreads();
    for (int off = 1; off < 256; off <<= 1) {
        int u = (t >= off) ? ls[t - off] : 0;
        __syncthreads();
        ls[t] += u;
        __syncthreads();
    }
    if (i < N) {
        int e = boff[blockIdx.x] + ls[t] - v;
        rowptr[i] = e;
        fill[i] = e;
    }
}

__global__ __launch_bounds__(256) void scatter_kernel(const int* __restrict__ ei,
                                                      int* __restrict__ fill,
                                                      int* __restrict__ col, int E, int N) {
    int i = blockIdx.x * 256 + threadIdx.x;
    int total = E + N;
    if (i >= total) return;
    int s, d;
    if (i < E) { s = ei[i]; d = ei[E + i]; }
    else       { s = i - E; d = s; }
    int pos = atomicAdd(&fill[d], 1);
    col[pos] = s;
}

// ---------------- weight prep: transpose + split fp32 -> bf16 hi/lo, [n][k] layout ----------------
__global__ __launch_bounds__(256) void w2t_prep_kernel(const float* __restrict__ W,
                                                       unsigned short* __restrict__ Th,
                                                       unsigned short* __restrict__ Tl) {
    int k = blockIdx.x, n = threadIdx.x;   // 256 x 256
    float w = W[k * 256 + n];
    unsigned short h = f2bf(w);
    unsigned short l = f2bf(w - bf2f(h));
    Th[n * 256 + k] = h;
    Tl[n * 256 + k] = l;
}

__global__ __launch_bounds__(256) void w3t_prep_kernel(const float* __restrict__ W,
                                                       unsigned short* __restrict__ Th,
                                                       unsigned short* __restrict__ Tl) {
    int n = blockIdx.x, k = threadIdx.x;   // 64 x 256
    float w = W[k * 64 + n];
    unsigned short h = f2bf(w);
    unsigned short l = f2bf(w - bf2f(h));
    Th[n * 256 + k] = h;
    Tl[n * 256 + k] = l;
}

#define LDK 40

// ---------------- layer-2 GEMM: split-bf16 MFMA, pre-split A, fused es/ed epilogue ----------------
// C[M,256] = A[M,256] @ W2[256,256]; A pre-split hi/lo bf16 (from agg4 layer-1 epilogue),
// W pre-split bf16 [n][k]. acc = hiA*hiB + hiA*loB + loA*hiB.
__global__ __launch_bounds__(256) void gemm2_mfma_kernel(const unsigned short* __restrict__ Ahb,
                                                         const unsigned short* __restrict__ Alb,
                                                         const unsigned short* __restrict__ WTh,
                                                         const unsigned short* __restrict__ WTl,
                                                         unsigned short* __restrict__ Cb,
                                                         const float* __restrict__ as_,
                                                         const float* __restrict__ ad_,
                                                         float* __restrict__ es,
                                                         float* __restrict__ ed,
                                                         int M) {
    __shared__ __align__(16) unsigned short Ah[128][LDK], Al[128][LDK];
    __shared__ __align__(16) unsigned short Bh[128][LDK], Bl[128][LDK];
    int tid  = threadIdx.x;
    int lane = tid & 63, wave = tid >> 6;
    int wm = wave >> 1, wn = wave & 1;
    int bm = blockIdx.x * 128;
    int bn = blockIdx.y * 128;
    int c = lane & 15, q = lane >> 4;

    f32x4 acc[4][4] = {};  // [mt][nt], C/D: row = q*4+r, col = c

    for (int k0 = 0; k0 < 256; k0 += 32) {
        // stage A: pure copy of pre-split bf16 (no conversion VALU)
        #pragma unroll
        for (int p = 0; p < 2; ++p) {
            int idx = p * 256 + tid;     // 0..511
            int r   = idx >> 2;          // 0..127
            int kc  = (idx & 3) * 8;     // 0,8,16,24
            int grow = bm + r;
            size_t go = (size_t)grow * 256 + k0 + kc;
            uint4 vh = make_uint4(0u,0u,0u,0u), vl = make_uint4(0u,0u,0u,0u);
            if (grow < M) {
                vh = *reinterpret_cast<const uint4*>(Ahb + go);
                vl = *reinterpret_cast<const uint4*>(Alb + go);
            }
            *reinterpret_cast<uint4*>(&Ah[r][kc]) = vh;
            *reinterpret_cast<uint4*>(&Al[r][kc]) = vl;
        }
        // stage B
        #pragma unroll
        for (int p = 0; p < 2; ++p) {
            int idx = p * 256 + tid;
            int n   = idx >> 2;
            int kc  = (idx & 3) * 8;
            const size_t go = (size_t)(bn + n) * 256 + k0 + kc;
            *reinterpret_cast<uint4*>(&Bh[n][kc]) = *reinterpret_cast<const uint4*>(WTh + go);
            *reinterpret_cast<uint4*>(&Bl[n][kc]) = *reinterpret_cast<const uint4*>(WTl + go);
        }
        __syncthreads();

        short8 bh[4], bl[4];
        #pragma unroll
        for (int nt = 0; nt < 4; ++nt) {
            bh[nt] = *reinterpret_cast<const short8*>(&Bh[wn * 64 + nt * 16 + c][q * 8]);
            bl[nt] = *reinterpret_cast<const short8*>(&Bl[wn * 64 + nt * 16 + c][q * 8]);
        }
        #pragma unroll
        for (int mt = 0; mt < 4; ++mt) {
            short8 ah = *reinterpret_cast<const short8*>(&Ah[wm * 64 + mt * 16 + c][q * 8]);
            short8 al = *reinterpret_cast<const short8*>(&Al[wm * 64 + mt * 16 + c][q * 8]);
            #pragma unroll
            for (int nt = 0; nt < 4; ++nt) {
                acc[mt][nt] = __builtin_amdgcn_mfma_f32_16x16x32_bf16(ah, bh[nt], acc[mt][nt], 0, 0, 0);
                acc[mt][nt] = __builtin_amdgcn_mfma_f32_16x16x32_bf16(ah, bl[nt], acc[mt][nt], 0, 0, 0);
                acc[mt][nt] = __builtin_amdgcn_mfma_f32_16x16x32_bf16(al, bh[nt], acc[mt][nt], 0, 0, 0);
            }
        }
        __syncthreads();
    }

    #pragma unroll
    for (int mt = 0; mt < 4; ++mt) {
        #pragma unroll
        for (int r = 0; r < 4; ++r) {
            int gr = bm + wm * 64 + mt * 16 + q * 4 + r;
            if (gr < M) {
                #pragma unroll
                for (int nt = 0; nt < 4; ++nt) {
                    Cb[(size_t)gr * 256 + bn + wn * 64 + nt * 16 + c] = f2bf(acc[mt][nt][r]);
                }
            }
        }
    }
    int head = blockIdx.y * 2 + wn;
    float asv[4], adv[4];
    #pragma unroll
    for (int nt = 0; nt < 4; ++nt) {
        asv[nt] = as_[head * 64 + nt * 16 + c];
        adv[nt] = ad_[head * 64 + nt * 16 + c];
    }
    #pragma unroll
    for (int mt = 0; mt < 4; ++mt) {
        #pragma unroll
        for (int r = 0; r < 4; ++r) {
            float s = 0.f, d = 0.f;
            #pragma unroll
            for (int nt = 0; nt < 4; ++nt) {
                s += acc[mt][nt][r] * asv[nt];
                d += acc[mt][nt][r] * adv[nt];
            }
            #pragma unroll
            for (int off = 1; off < 16; off <<= 1) {
                s += __shfl_xor(s, off, 64);
                d += __shfl_xor(d, off, 64);
            }
            int gr = bm + wm * 64 + mt * 16 + q * 4 + r;
            if (c == 0 && gr < M) {
                es[(size_t)gr * 4 + head] = s;
                ed[(size_t)gr * 4 + head] = d;
            }
        }
    }
}

// ---------------- layer-3 GEMM: bf16-A MFMA, W3 split hi/lo ----------------
__global__ __launch_bounds__(256) void gemm3_mfma_kernel(const unsigned short* __restrict__ Ab,
                                                         const unsigned short* __restrict__ WTh,
                                                         const unsigned short* __restrict__ WTl,
                                                         unsigned short* __restrict__ Cb,
                                                         const float* __restrict__ as_,
                                                         const float* __restrict__ ad_,
                                                         float* __restrict__ es,
                                                         float* __restrict__ ed,
                                                         int M) {
    __shared__ __align__(16) unsigned short Ah[128][LDK];
    __shared__ __align__(16) unsigned short Bh[64][LDK], Bl[64][LDK];
    int tid = threadIdx.x, lane = tid & 63, wave = tid >> 6;
    int bm = blockIdx.x * 128;
    int c = lane & 15, q = lane >> 4;
    f32x4 acc[2][4] = {};

    for (int k0 = 0; k0 < 256; k0 += 32) {
        #pragma unroll
        for (int p = 0; p < 2; ++p) {
            int idx = p * 256 + tid;
            int r   = idx >> 2;
            int kf  = (idx & 3) * 8;
            int grow = bm + r;
            uint4 v = (grow < M)
                ? *reinterpret_cast<const uint4*>(Ab + (size_t)grow * 256 + k0 + kf)
                : make_uint4(0u, 0u, 0u, 0u);
            *reinterpret_cast<uint4*>(&Ah[r][kf]) = v;
        }
        {
            int n  = tid >> 2;
            int kc = (tid & 3) * 8;
            size_t go = (size_t)n * 256 + k0 + kc;
            *reinterpret_cast<uint4*>(&Bh[n][kc]) = *reinterpret_cast<const uint4*>(WTh + go);
            *reinterpret_cast<uint4*>(&Bl[n][kc]) = *reinterpret_cast<const uint4*>(WTl + go);
        }
        __syncthreads();

        short8 bh[4], bl[4];
        #pragma unroll
        for (int nt = 0; nt < 4; ++nt) {
            bh[nt] = *reinterpret_cast<const short8*>(&Bh[nt * 16 + c][q * 8]);
            bl[nt] = *reinterpret_cast<const short8*>(&Bl[nt * 16 + c][q * 8]);
        }
        #pragma unroll
        for (int mt = 0; mt < 2; ++mt) {
            short8 a = *reinterpret_cast<const short8*>(&Ah[wave * 32 + mt * 16 + c][q * 8]);
            #pragma unroll
            for (int nt = 0; nt < 4; ++nt) {
                acc[mt][nt] = __builtin_amdgcn_mfma_f32_16x16x32_bf16(a, bh[nt], acc[mt][nt], 0, 0, 0);
                acc[mt][nt] = __builtin_amdgcn_mfma_f32_16x16x32_bf16(a, bl[nt], acc[mt][nt], 0, 0, 0);
            }
        }
        __syncthreads();
    }

    float asv[4], adv[4];
    #pragma unroll
    for (int nt = 0; nt < 4; ++nt) { asv[nt] = as_[nt * 16 + c]; adv[nt] = ad_[nt * 16 + c]; }
    #pragma unroll
    for (int mt = 0; mt < 2; ++mt) {
        #pragma unroll
        for (int r = 0; r < 4; ++r) {
            int gr = bm + wave * 32 + mt * 16 + q * 4 + r;
            bool ok = gr < M;
            if (ok) {
                #pragma unroll
                for (int nt = 0; nt < 4; ++nt)
                    Cb[(size_t)gr * 64 + nt * 16 + c] = f2bf(acc[mt][nt][r]);
            }
            float s = 0.f, d = 0.f;
            #pragma unroll
            for (int nt = 0; nt < 4; ++nt) {
                s += acc[mt][nt][r] * asv[nt];
                d += acc[mt][nt][r] * adv[nt];
            }
            #pragma unroll
            for (int off = 1; off < 16; off <<= 1) {
                s += __shfl_xor(s, off, 64);
                d += __shfl_xor(d, off, 64);
            }
            if (c == 0 && ok) { es[gr] = s; ed[gr] = d; }
        }
    }
}

// ---------------- layer-1 fp32 GEMM (K=16) with fused es/ed epilogue ----------------
template <int H>
__global__ __launch_bounds__(256) void gemm_attn_kernel(const float* __restrict__ A,
                                                        const float* __restrict__ B,
                                                        unsigned short* __restrict__ Cb,
                                                        const float* __restrict__ as_,
                                                        const float* __restrict__ ad_,
                                                        float* __restrict__ es,
                                                        float* __restrict__ ed,
                                                        int M, int K, int Ncol) {
    __shared__ __align__(16) float As[16][64];
    __shared__ __align__(16) float Bs[16][64];
    int tid = threadIdx.x;
    int bm = blockIdx.x * 64;
    int bn = blockIdx.y * 64;
    int tm = (tid >> 4) * 4;
    int tn = (tid & 15) * 4;
    float acc[4][4] = {};
    int ar  = tid >> 2;
    int akk = (tid & 3) * 4;
    int brr = tid >> 4;
    int bcc = (tid & 15) * 4;
    for (int k0 = 0; k0 < K; k0 += 16) {
        int grow = bm + ar;
        float4 av;
        if (grow < M) av = *reinterpret_cast<const float4*>(A + (size_t)grow * K + k0 + akk);
        else          av = make_float4(0.f, 0.f, 0.f, 0.f);
        As[akk + 0][ar] = av.x;
        As[akk + 1][ar] = av.y;
        As[akk + 2][ar] = av.z;
        As[akk + 3][ar] = av.w;
        float4 bv = *reinterpret_cast<const float4*>(B + (size_t)(k0 + brr) * Ncol + bn + bcc);
        *reinterpret_cast<float4*>(&Bs[brr][bcc]) = bv;
        __syncthreads();
        #pragma unroll
        for (int kk = 0; kk < 16; ++kk) {
            float4 a4 = *reinterpret_cast<const float4*>(&As[kk][tm]);
            float4 b4 = *reinterpret_cast<const float4*>(&Bs[kk][tn]);
            float a[4] = {a4.x, a4.y, a4.z, a4.w};
            float b[4] = {b4.x, b4.y, b4.z, b4.w};
            #pragma unroll
            for (int i = 0; i < 4; ++i)
                #pragma unroll
                for (int j = 0; j < 4; ++j) acc[i][j] += a[i] * b[j];
        }
        __syncthreads();
    }
    #pragma unroll
    for (int i = 0; i < 4; ++i) {
        int gr = bm + tm + i;
        if (gr < M) {
            ushort4 r;
            r.x = f2bf(acc[i][0]); r.y = f2bf(acc[i][1]);
            r.z = f2bf(acc[i][2]); r.w = f2bf(acc[i][3]);
            *reinterpret_cast<ushort4*>(Cb + (size_t)gr * Ncol + bn + tn) = r;
        }
    }
    int hy = blockIdx.y;
    float4 asv = *reinterpret_cast<const float4*>(as_ + (size_t)hy * 64 + tn);
    float4 adv = *reinterpret_cast<const float4*>(ad_ + (size_t)hy * 64 + tn);
    float sv[4], dv[4];
    #pragma unroll
    for (int i = 0; i < 4; ++i) {
        sv[i] = acc[i][0] * asv.x + acc[i][1] * asv.y + acc[i][2] * asv.z + acc[i][3] * asv.w;
        dv[i] = acc[i][0] * adv.x + acc[i][1] * adv.y + acc[i][2] * adv.z + acc[i][3] * adv.w;
    }
    #pragma unroll
    for (int off = 1; off < 16; off <<= 1) {
        #pragma unroll
        for (int i = 0; i < 4; ++i) {
            sv[i] += __shfl_xor(sv[i], off, 64);
            dv[i] += __shfl_xor(dv[i], off, 64);
        }
    }
    if ((tid & 15) == 0) {
        #pragma unroll
        for (int i = 0; i < 4; ++i) {
            int gr = bm + tm + i;
            if (gr < M) {
                es[(size_t)gr * H + hy] = sv[i];
                ed[(size_t)gr * H + hy] = dv[i];
            }
        }
    }
}

__device__ __forceinline__ float lrelu02(float x) { return x > 0.f ? x : 0.2f * x; }
__device__ __forceinline__ float eluf(float x)    { return x > 0.f ? x : expm1f(x); }

// ---------------- fused per-dst aggregation, H=4, bf16 gather, single-pass softmax ----------------
// Half-wave-per-edge gather: 32 lanes x 8 dims (uint4 = 16 B/lane), 2 edges per wave-iter.
// OUTMODE: 0 = fp32, 1 = bf16 (gemm3 A), 2 = pre-split hi/lo bf16 (gemm2 A).
template <int ACT, int OUTMODE>
__global__ __launch_bounds__(256) void agg4_kernel(const unsigned short* __restrict__ hb,
                                                   const float* __restrict__ es,
                                                   const float* __restrict__ ed,
                                                   const int* __restrict__ rowptr,
                                                   const int* __restrict__ col,
                                                   const float* __restrict__ bias,
                                                   void* __restrict__ outp,
                                                   void* __restrict__ outp2, int N) {
    __shared__ int   slds[4][64];
    __shared__ float plds[4][4][68];   // +4 pad: heads land in different banks
    int sub  = threadIdx.x >> 6;
    int lane = threadIdx.x & 63;
    int node = blockIdx.x * 4 + sub;
    if (node >= N) return;
    int s = rowptr[node], t = rowptr[node + 1];

    float edv[4];
    #pragma unroll
    for (int h = 0; h < 4; ++h) edv[h] = ed[(size_t)node * 4 + h];

    int half = lane >> 5, sl = lane & 31;
    int hh8 = sl >> 3;                  // head of this lane's 8-dim slice
    float den[4] = {0.f, 0.f, 0.f, 0.f};
    float4 a0 = make_float4(0.f, 0.f, 0.f, 0.f);   // dims sl*8 .. +3
    float4 a1 = make_float4(0.f, 0.f, 0.f, 0.f);   // dims sl*8+4 .. +7

    for (int base = s; base < t; base += 64) {
        int j = base + lane;
        int m = t - base; if (m > 64) m = 64;
        int sc = 0;
        float p[4] = {0.f, 0.f, 0.f, 0.f};
        if (j < t) {
            sc = col[j];
            float4 e4 = *reinterpret_cast<const float4*>(es + (size_t)sc * 4);
            p[0] = __expf(lrelu02(e4.x + edv[0]));
            p[1] = __expf(lrelu02(e4.y + edv[1]));
            p[2] = __expf(lrelu02(e4.z + edv[2]));
            p[3] = __expf(lrelu02(e4.w + edv[3]));
        }
        slds[sub][lane] = sc;
        #pragma unroll
        for (int h = 0; h < 4; ++h) {
            den[h] += p[h];
            plds[sub][h][lane] = p[h];
        }
        // gather: 2 edges per iteration (one per half-wave); phantom odd edge has p=0
        int nit = (m + 1) >> 1;
        #pragma unroll 4
        for (int it = 0; it < nit; ++it) {
            int idx = 2 * it + half;
            int scj = slds[sub][idx];
            float a = plds[sub][hh8][idx];
            uint4 u = *reinterpret_cast<const uint4*>(hb + (size_t)scj * 256 + sl * 8);
            a0.x += bflo(u.x) * a;
            a0.y += bfhi(u.x) * a;
            a0.z += bflo(u.y) * a;
            a0.w += bfhi(u.y) * a;
            a1.x += bflo(u.z) * a;
            a1.y += bfhi(u.z) * a;
            a1.z += bflo(u.w) * a;
            a1.w += bfhi(u.w) * a;
        }
    }
    // combine halves (even-edge + odd-edge partial sums)
    a0.x += __shfl_xor(a0.x, 32, 64);
    a0.y += __shfl_xor(a0.y, 32, 64);
    a0.z += __shfl_xor(a0.z, 32, 64);
    a0.w += __shfl_xor(a0.w, 32, 64);
    a1.x += __shfl_xor(a1.x, 32, 64);
    a1.y += __shfl_xor(a1.y, 32, 64);
    a1.z += __shfl_xor(a1.z, 32, 64);
    a1.w += __shfl_xor(a1.w, 32, 64);
    #pragma unroll
    for (int off = 32; off; off >>= 1)
        #pragma unroll
        for (int h = 0; h < 4; ++h) den[h] += __shfl_xor(den[h], off, 64);

    if (half == 0) {
        float inv = 1.f / den[hh8];
        float4 bv0 = *reinterpret_cast<const float4*>(bias + sl * 8);
        float4 bv1 = *reinterpret_cast<const float4*>(bias + sl * 8 + 4);
        float r[8];
        r[0] = a0.x * inv + bv0.x; r[1] = a0.y * inv + bv0.y;
        r[2] = a0.z * inv + bv0.z; r[3] = a0.w * inv + bv0.w;
        r[4] = a1.x * inv + bv1.x; r[5] = a1.y * inv + bv1.y;
        r[6] = a1.z * inv + bv1.z; r[7] = a1.w * inv + bv1.w;
        if (ACT) {
            #pragma unroll
            for (int e = 0; e < 8; ++e) r[e] = eluf(r[e]);
        }
        if constexpr (OUTMODE == 0) {
            float* o = (float*)outp + (size_t)node * 256 + sl * 8;
            *reinterpret_cast<float4*>(o)     = make_float4(r[0], r[1], r[2], r[3]);
            *reinterpret_cast<float4*>(o + 4) = make_float4(r[4], r[5], r[6], r[7]);
        } else if constexpr (OUTMODE == 1) {
            unsigned short ob[8];
            #pragma unroll
            for (int e = 0; e < 8; ++e) ob[e] = f2bf(r[e]);
            *reinterpret_cast<uint4*>((unsigned short*)outp + (size_t)node * 256 + sl * 8) =
                *reinterpret_cast<const uint4*>(ob);
        } else {
            unsigned short oh[8], ol[8];
            #pragma unroll
            for (int e = 0; e < 8; ++e) {
                oh[e] = f2bf(r[e]);
                ol[e] = f2bf(r[e] - bf2f(oh[e]));
            }
            size_t o = (size_t)node * 256 + sl * 8;
            *reinterpret_cast<uint4*>((unsigned short*)outp  + o) = *reinterpret_cast<const uint4*>(oh);
            *reinterpret_cast<uint4*>((unsigned short*)outp2 + o) = *reinterpret_cast<const uint4*>(ol);
        }
    }
}

// ---------------- fused per-dst aggregation, H=1, bf16 gather, single-pass ----------------
__global__ __launch_bounds__(256) void agg1_kernel(const unsigned short* __restrict__ hb,
                                                   const float* __restrict__ es,
                                                   const float* __restrict__ ed,
                                                   const int* __restrict__ rowptr,
                                                   const int* __restrict__ col,
                                                   const float* __restrict__ bias,
                                                   float* __restrict__ out, int N) {
    __shared__ int   slds[4][64];
    __shared__ float plds[4][64];
    int sub  = threadIdx.x >> 6;
    int lane = threadIdx.x & 63;
    int node = blockIdx.x * 4 + sub;
    if (node >= N) return;
    int s = rowptr[node], t = rowptr[node + 1];
    float edv = ed[node];

    float den = 0.f, acc = 0.f;
    for (int base = s; base < t; base += 64) {
        int j = base + lane;
        int m = t - base; if (m > 64) m = 64;
        int sc = 0;
        float p0 = 0.f;
        if (j < t) {
            sc = col[j];
            p0 = __expf(lrelu02(es[sc] + edv));
        }
        slds[sub][lane] = sc;
        plds[sub][lane] = p0;
        den += p0;
        #pragma unroll 4
        for (int jj = 0; jj < m; ++jj) {
            int scj = slds[sub][jj];
            float a = plds[sub][jj];
            acc += bf2f(hb[(size_t)scj * 64 + lane]) * a;
        }
    }
    #pragma unroll
    for (int off = 32; off; off >>= 1) den += __shfl_xor(den, off, 64);
    out[(size_t)node * 64 + lane] = acc * (1.f / den) + bias[lane];
}

// ---------------- graph mean ----------------
__global__ __launch_bounds__(256) void gmean_partial(const float* __restrict__ ne,
                                                     float* __restrict__ part, int N) {
    int d = threadIdx.x & 63, sub = threadIdx.x >> 6;
    int start = blockIdx.x * 4 + sub;
    float s = 0.f;
    for (int n = start; n < N; n += gridDim.x * 4) s += ne[(size_t)n * 64 + d];
    __shared__ float ls[256];
    ls[threadIdx.x] = s;
    __syncthreads();
    if (threadIdx.x < 64) {
        float v = ls[threadIdx.x] + ls[threadIdx.x + 64] + ls[threadIdx.x + 128] + ls[threadIdx.x + 192];
        part[blockIdx.x * 64 + d] = v;
    }
}

__global__ __launch_bounds__(64) void gmean_final(const float* __restrict__ part,
                                                  float* __restrict__ gout, int nblk, float invN) {
    int d = threadIdx.x;
    float s = 0.f;
    for (int b = 0; b < nblk; ++b) s += part[b * 64 + d];
    gout[d] = s * invN;
}

extern "C" void kernel_launch(void* const* d_in, const int* in_sizes, int n_in,
                              void* d_out, int out_size, void* d_ws, size_t ws_size,
                              hipStream_t stream) {
    const float* x   = (const float*)d_in[0];
    const int*   ei  = (const int*)d_in[1];
    const float* W1  = (const float*)d_in[2];
    const float* a1s = (const float*)d_in[3];
    const float* a1d = (const float*)d_in[4];
    const float* b1  = (const float*)d_in[5];
    const float* W2  = (const float*)d_in[6];
    const float* a2s = (const float*)d_in[7];
    const float* a2d = (const float*)d_in[8];
    const float* b2  = (const float*)d_in[9];
    const float* W3  = (const float*)d_in[10];
    const float* a3s = (const float*)d_in[11];
    const float* a3d = (const float*)d_in[12];
    const float* b3  = (const float*)d_in[13];
    float* out = (float*)d_out;

    const int N = NNODES;
    const int E = in_sizes[1] / 2;  // 800000
    const int NB = (N + 255) / 256;

    // workspace carve (16B alignment maintained)
    char* w = (char*)d_ws;
    unsigned short* Hb   = (unsigned short*)w; w += (size_t)N * 256 * 2;  // h1/h2 bf16 (agg4 gather)
    unsigned short* B0b  = (unsigned short*)w; w += (size_t)N * 256 * 2;  // agg2 out bf16 (gemm3 A)
    unsigned short* H3b  = (unsigned short*)w; w += (size_t)N * 64 * 2;   // h3 bf16 (agg1 gather)
    unsigned short* A1h  = (unsigned short*)w; w += (size_t)N * 256 * 2;  // agg1(layer1) out hi (gemm2 A)
    unsigned short* A1l  = (unsigned short*)w; w += (size_t)N * 256 * 2;  // agg1(layer1) out lo
    float* es = (float*)w; w += (size_t)N * 4 * 4;
    float* ed = (float*)w; w += (size_t)N * 4 * 4;
    unsigned short* W2Th = (unsigned short*)w; w += 256 * 256 * 2;
    unsigned short* W2Tl = (unsigned short*)w; w += 256 * 256 * 2;
    unsigned short* W3Th = (unsigned short*)w; w += 64 * 256 * 2;
    unsigned short* W3Tl = (unsigned short*)w; w += 64 * 256 * 2;
    int* deg    = (int*)w; w += (size_t)N * 4;
    int* rowptr = (int*)w; w += (size_t)(N + 2) * 4;
    int* fill   = (int*)w; w += (size_t)N * 4;
    int* col    = (int*)w; w += (size_t)(E + N) * 4;
    int* bsum   = (int*)w; w += 256 * 4;
    int* boff   = (int*)w; w += 256 * 4;
    float* part = (float*)w; w += 128 * 64 * 4;
    (void)ws_size; (void)n_in; (void)out_size;

    // ---- CSR build ----
    deg_init_kernel<<<NB, 256, 0, stream>>>(deg, N);
    deg_count_kernel<<<(E + 255) / 256, 256, 0, stream>>>(ei, deg, E);
    scan_partial_kernel<<<NB, 256, 0, stream>>>(deg, bsum, N);
    scan_blocks_kernel<<<1, 256, 0, stream>>>(bsum, boff, rowptr + N, NB);
    scan_final_kernel<<<NB, 256, 0, stream>>>(deg, boff, rowptr, fill, N);
    scatter_kernel<<<(E + N + 255) / 256, 256, 0, stream>>>(ei, fill, col, E, N);
    // weight prep
    w2t_prep_kernel<<<256, 256, 0, stream>>>(W2, W2Th, W2Tl);
    w3t_prep_kernel<<<64, 256, 0, stream>>>(W3, W3Th, W3Tl);

    // ---- Layer 1: x[N,16] @ W1[16,256], fp32 VALU, C->bf16 ----
    gemm_attn_kernel<4><<<dim3((N + 63) / 64, 4), 256, 0, stream>>>(
        x, W1, Hb, a1s, a1d, es, ed, N, 16, 256);
    agg4_kernel<1, 2><<<(N + 3) / 4, 256, 0, stream>>>(Hb, es, ed, rowptr, col, b1, A1h, A1l, N);

    // ---- Layer 2: (A1h+A1l)[N,256] @ W2, split-bf16 MFMA ----
    gemm2_mfma_kernel<<<dim3((N + 127) / 128, 2), 256, 0, stream>>>(
        A1h, A1l, W2Th, W2Tl, Hb, a2s, a2d, es, ed, N);
    agg4_kernel<1, 1><<<(N + 3) / 4, 256, 0, stream>>>(Hb, es, ed, rowptr, col, b2, B0b, nullptr, N);

    // ---- Layer 3: B0b[N,256] @ W3, bf16-A MFMA ----
    gemm3_mfma_kernel<<<(N + 127) / 128, 256, 0, stream>>>(
        B0b, W3Th, W3Tl, H3b, a3s, a3d, es, ed, N);
    agg1_kernel<<<(N + 3) / 4, 256, 0, stream>>>(H3b, es, ed, rowptr, col, b3, out, N);

    // ---- graph mean ----
    gmean_partial<<<128, 256, 0, stream>>>(out, part, N);
    gmean_final<<<1, 64, 0, stream>>>(part, out + (size_t)N * 64, 128, 1.0f / N);
}